// Round 10
// baseline (119.477 us; speedup 1.0000x reference)
//
#include <hip/hip_runtime.h>

#define PI_F 3.14159265358979323846f

typedef float v2f __attribute__((ext_vector_type(2)));
typedef float v4f __attribute__((ext_vector_type(4)));

// packed dual-FMA, all-VGPR operands, value broadcast via op_sel
// acc.x += w.x*v.x; acc.y += w.y*v.x
__device__ __forceinline__ void pkfma_lo(v2f& d, v2f w, v2f v) {
    asm("v_pk_fma_f32 %0, %1, %2, %0 op_sel:[0,0,0] op_sel_hi:[1,0,1]"
        : "+v"(d) : "v"(w), "v"(v));
}
// acc.x += w.x*v.y; acc.y += w.y*v.y
__device__ __forceinline__ void pkfma_hi(v2f& d, v2f w, v2f v) {
    asm("v_pk_fma_f32 %0, %1, %2, %0 op_sel:[0,1,0] op_sel_hi:[1,1,1]"
        : "+v"(d) : "v"(w), "v"(v));
}

// ---------------- K0: weight transpose ----------------
// wt1: [ic][kd][kh][oc 8] ; wt2: [ic][kd][kh][oc pad 12]
__global__ void k_prep(const float* __restrict__ w1, const float* __restrict__ w2,
                       float* __restrict__ wt1, float* __restrict__ wt2) {
    const int tid = threadIdx.x;
    for (int i = tid; i < 1568; i += 256) {
        const int oc = i / 196, rem = i % 196;   // rem = ic*49 + kd*7 + kh
        wt1[rem * 8 + oc] = w1[i];
    }
    for (int i = tid; i < 2400; i += 256) wt2[i] = 0.f;
    __syncthreads();
    for (int i = tid; i < 2000; i += 256) {
        const int oc = i / 200, rem = i % 200;   // rem = ic*25 + kd*5 + kh
        wt2[rem * 12 + oc] = w2[i];
    }
}

// ---------------- K1: conv1 7x7 (4->8) + maxpool 2x2 + bias + relu ----------------
// x:(8,4,128,128,8) -> h1:(8,8,61,61,8).
// Tile 4x4 pooled -> 2048 blocks (8/CU). 256 threads = pp(16) x cp(4) x wq(4, w-pair).
// Per tap: 1 ds_read_b64 + 8 pkfma. Weights: UNIFORM GLOBAL vector loads (vmcnt,
// decoupled from ds_read's lgkmcnt -> no scalar-load serialization). Double-buffered
// input, 1 barrier/ic.
__global__ __launch_bounds__(256) void k_conv1(const float* __restrict__ x,
                                               const float* __restrict__ wt1,
                                               const float* __restrict__ b1,
                                               float* __restrict__ h1) {
    const int b = blockIdx.y;
    const int ty = blockIdx.x >> 4, tx = blockIdx.x & 15;   // 16 x 16 tiles
    const int py0 = ty * 4, px0 = tx * 4;
    const int iy0 = py0 * 2, ix0 = px0 * 2;

    __shared__ float tin[2][14 * 120];     // 2 x 6720 B (14 rows x 30 f4)

    const int tid = threadIdx.x;
    const int wq  = tid & 3;               // w-pair: floats {2wq, 2wq+1}
    const int cp  = (tid >> 2) & 3;
    const int cpx = cp & 1, cpy = cp >> 1;
    const int pp  = tid >> 4;              // 0..15
    const int pl  = pp >> 2, pj = pp & 3;
    const int cy  = 2 * pl + cpy, cx = 2 * pj + cpx;

    // staging: 392 data f4 (14 rows x 28)
    size_t sOff[2]; int sLds[2];
    const bool sAct1 = (tid < 136);
    {
        int idxs[2] = {tid, (tid + 256 < 392) ? tid + 256 : 391};
#pragma unroll
        for (int s = 0; s < 2; ++s) {
            const int r = idxs[s] / 28, c4 = idxs[s] % 28;
            const int row = min(iy0 + r, 127), col = min(ix0 + (c4 >> 1), 127);
            sOff[s] = ((size_t)row * 128 + col) * 8 + (c4 & 1) * 4;
            sLds[s] = r * 120 + c4 * 4;
        }
    }

    v2f acc[4][2];   // [oc pair][w in pair]
#pragma unroll
    for (int p = 0; p < 4; ++p) { acc[p][0] = (v2f)(0.f); acc[p][1] = (v2f)(0.f); }

    {   // prologue: stage ic=0 into buf 0
        const float* xb = x + (size_t)b * 4 * 131072;
        float4 r0 = *reinterpret_cast<const float4*>(xb + sOff[0]);
        float4 r1 = *reinterpret_cast<const float4*>(xb + sOff[1]);
        *reinterpret_cast<float4*>(&tin[0][sLds[0]]) = r0;
        if (sAct1) *reinterpret_cast<float4*>(&tin[0][sLds[1]]) = r1;
    }
    __syncthreads();

    for (int ic = 0; ic < 4; ++ic) {
        float4 r0, r1;
        const bool pf = (ic < 3);
        if (pf) {   // issue next-ic loads early; complete under compute
            const float* xb = x + ((size_t)b * 4 + ic + 1) * 131072;
            r0 = *reinterpret_cast<const float4*>(xb + sOff[0]);
            r1 = *reinterpret_cast<const float4*>(xb + sOff[1]);
        }
        const float* tbuf = tin[ic & 1];
#pragma unroll
        for (int kd = 0; kd < 7; ++kd) {
            const float* vrow = &tbuf[(cy + kd) * 120 + cx * 8 + 2 * wq];
            const float* wb = wt1 + (ic * 7 + kd) * 56;   // global, uniform across wave
#pragma unroll
            for (int kh = 0; kh < 7; ++kh) {
                const v2f v = *reinterpret_cast<const v2f*>(vrow + kh * 8);
#pragma unroll
                for (int p = 0; p < 4; ++p) {
                    const v2f wp = *reinterpret_cast<const v2f*>(wb + kh * 8 + 2 * p);
                    pkfma_lo(acc[p][0], wp, v);
                    pkfma_hi(acc[p][1], wp, v);
                }
            }
        }
        if (pf) {
            float* nb = tin[(ic + 1) & 1];
            *reinterpret_cast<float4*>(&nb[sLds[0]]) = r0;
            if (sAct1) *reinterpret_cast<float4*>(&nb[sLds[1]]) = r1;
            __syncthreads();
        }
    }

    // pool: cpx = lane bit2 (shfl_xor 4), cpy = lane bit3 (shfl_xor 8)
    const int pi = py0 + pl, pjg = px0 + pj;
    const bool doStore = (cp == 0) && (pi < 61) && (pjg < 61);
#pragma unroll
    for (int p = 0; p < 4; ++p) {
        const float be = b1[2 * p], bo = b1[2 * p + 1];
        float ex[2], ox[2];
#pragma unroll
        for (int w = 0; w < 2; ++w) {
            float a = acc[p][w].x, c = acc[p][w].y;
            a = fmaxf(a, __shfl_xor(a, 4)); a = fmaxf(a, __shfl_xor(a, 8));
            c = fmaxf(c, __shfl_xor(c, 4)); c = fmaxf(c, __shfl_xor(c, 8));
            ex[w] = fmaxf(a + be, 0.f);
            ox[w] = fmaxf(c + bo, 0.f);
        }
        if (doStore) {
            *reinterpret_cast<float2*>(
                h1 + ((((size_t)b * 8 + 2 * p) * 61 + pi) * 61 + pjg) * 8 + 2 * wq) =
                make_float2(ex[0], ex[1]);
            *reinterpret_cast<float2*>(
                h1 + ((((size_t)b * 8 + 2 * p + 1) * 61 + pi) * 61 + pjg) * 8 + 2 * wq) =
                make_float2(ox[0], ox[1]);
        }
    }
}

// ---------------- K2: conv2 5x5 (8->10) + maxpool 2x2 + bias + relu ----------------
// h1:(8,8,61,61,8) -> h2:(8,10,28,28,8).
// Tile 2x4 pooled, 4 waves, ic split 2/wave; weights via uniform global v2f loads.
__global__ __launch_bounds__(256) void k_conv2(const float* __restrict__ h1,
                                               const float* __restrict__ wt2,
                                               const float* __restrict__ b2,
                                               float* __restrict__ h2) {
    const int b = blockIdx.y;
    const int ty = blockIdx.x / 7, tx = blockIdx.x % 7;    // 14 x 7 tiles
    const int py0 = ty * 2, px0 = tx * 4;
    const int iy0 = py0 * 2, ix0 = px0 * 2;

    __shared__ float smem[7680];

    const int tid = threadIdx.x;
    {
        const float* hb = h1 + (size_t)b * 8 * 29768;
#pragma unroll
        for (int k = 0; k < 6; ++k) {
            const int s = tid + k * 256;            // < 1536
            const int ic = s / 192, rem = s % 192;
            const int r = rem / 24, c4 = rem % 24;
            const float4 v = *reinterpret_cast<const float4*>(
                hb + (size_t)ic * 29768 + ((size_t)(iy0 + r) * 61 + ix0 + (c4 >> 1)) * 8 + (c4 & 1) * 4);
            *reinterpret_cast<float4*>(&smem[(ic * 216 + r * 27 + c4) * 4]) = v;
        }
    }
    __syncthreads();

    const int wave = tid >> 6, lane = tid & 63;
    const int wq = lane & 1;
    const int cp = (lane >> 1) & 3;
    const int pp = lane >> 3;
    const int pl = pp >> 2, pj = pp & 3;
    const int cy = 2 * pl + (cp >> 1), cx = 2 * pj + (cp & 1);

    v2f acc[5][4];
#pragma unroll
    for (int p = 0; p < 5; ++p)
#pragma unroll
        for (int w = 0; w < 4; ++w) acc[p][w] = (v2f)(0.f);

#pragma unroll
    for (int ic2 = 0; ic2 < 2; ++ic2) {
        const int ic = 2 * wave + ic2;
#pragma unroll
        for (int kd = 0; kd < 5; ++kd) {
            const float* vrow = &smem[ic * 864 + (cy + kd) * 108 + cx * 8 + wq * 4];
            const float* wrow = wt2 + (ic * 25 + kd * 5) * 12;   // global, uniform
#pragma unroll
            for (int kh = 0; kh < 5; ++kh) {
                const v4f vq = *reinterpret_cast<const v4f*>(vrow + kh * 8);
                const v2f v01 = __builtin_shufflevector(vq, vq, 0, 1);
                const v2f v23 = __builtin_shufflevector(vq, vq, 2, 3);
#pragma unroll
                for (int p = 0; p < 5; ++p) {
                    const v2f wp = *reinterpret_cast<const v2f*>(wrow + kh * 12 + 2 * p);
                    pkfma_lo(acc[p][0], wp, v01);
                    pkfma_hi(acc[p][1], wp, v01);
                    pkfma_lo(acc[p][2], wp, v23);
                    pkfma_hi(acc[p][3], wp, v23);
                }
            }
        }
    }
    __syncthreads();
    if (wave > 0) {
        float* dst = &smem[((wave - 1) * 64 + lane) * 40];
#pragma unroll
        for (int p = 0; p < 5; ++p)
#pragma unroll
            for (int w = 0; w < 4; ++w)
                *reinterpret_cast<v2f*>(dst + (p * 4 + w) * 2) = acc[p][w];
    }
    __syncthreads();
    if (wave == 0) {
#pragma unroll
        for (int v = 0; v < 3; ++v) {
            const float* src = &smem[(v * 64 + lane) * 40];
#pragma unroll
            for (int p = 0; p < 5; ++p)
#pragma unroll
                for (int w = 0; w < 4; ++w)
                    acc[p][w] += *reinterpret_cast<const v2f*>(src + (p * 4 + w) * 2);
        }
        const int pi = py0 + pl, pjg = px0 + pj;
        const bool doStore = (cp == 0);
#pragma unroll
        for (int p = 0; p < 5; ++p) {
            const float be = b2[2 * p], bo = b2[2 * p + 1];
            float e[4], o[4];
#pragma unroll
            for (int w = 0; w < 4; ++w) {
                float a = acc[p][w].x, c = acc[p][w].y;
                a = fmaxf(a, __shfl_xor(a, 2)); a = fmaxf(a, __shfl_xor(a, 4));
                c = fmaxf(c, __shfl_xor(c, 2)); c = fmaxf(c, __shfl_xor(c, 4));
                e[w] = fmaxf(a + be, 0.f);
                o[w] = fmaxf(c + bo, 0.f);
            }
            if (doStore) {
                *reinterpret_cast<float4*>(
                    h2 + ((((size_t)b * 10 + 2 * p) * 28 + pi) * 28 + pjg) * 8 + wq * 4) =
                    make_float4(e[0], e[1], e[2], e[3]);
                *reinterpret_cast<float4*>(
                    h2 + ((((size_t)b * 10 + 2 * p + 1) * 28 + pi) * 28 + pjg) * 8 + wq * 4) =
                    make_float4(o[0], o[1], o[2], o[3]);
            }
        }
    }
}

// ---------------- K3: fc1 (62720 -> 32), split-K, partials to ws ----------------
__global__ __launch_bounds__(256) void k_fc1(const float* __restrict__ feat,
                                             const float* __restrict__ w,
                                             float* __restrict__ partials) {
    const int j = blockIdx.x >> 4;
    const int kc = blockIdx.x & 15;
    const int k0 = kc * 3920;
    const float4* w4 = reinterpret_cast<const float4*>(w + (size_t)j * 62720 + k0);
    float acc[8];
#pragma unroll
    for (int b = 0; b < 8; ++b) acc[b] = 0.f;
    for (int i = threadIdx.x; i < 980; i += 256) {
        const float4 wv = w4[i];
#pragma unroll
        for (int b = 0; b < 8; ++b) {
            const float4 fv = *reinterpret_cast<const float4*>(feat + (size_t)b * 62720 + k0 + i * 4);
            acc[b] = fmaf(wv.x, fv.x, fmaf(wv.y, fv.y, fmaf(wv.z, fv.z, fmaf(wv.w, fv.w, acc[b]))));
        }
    }
#pragma unroll
    for (int b = 0; b < 8; ++b)
#pragma unroll
        for (int off = 32; off > 0; off >>= 1) acc[b] += __shfl_down(acc[b], off);
    __shared__ float red[4][8];
    const int wave = threadIdx.x >> 6;
    if ((threadIdx.x & 63) == 0)
#pragma unroll
        for (int b = 0; b < 8; ++b) red[wave][b] = acc[b];
    __syncthreads();
    if (threadIdx.x < 8) {
        partials[(j * 16 + kc) * 8 + threadIdx.x] =
            red[0][threadIdx.x] + red[1][threadIdx.x] + red[2][threadIdx.x] + red[3][threadIdx.x];
    }
}

// ---------------- K4: fc1-reduce + bias/relu + fc2 + tanh + rigid + moved/reg ----------
__global__ __launch_bounds__(1024) void k_fc2_moved(const float* __restrict__ partials,
                                                    const float* __restrict__ f1b,
                                                    const float* __restrict__ w,
                                                    const float* __restrict__ bias,
                                                    const float* __restrict__ pos,
                                                    const float* __restrict__ centers,
                                                    float* __restrict__ rt,
                                                    float* __restrict__ movedOut,
                                                    float* __restrict__ regOut) {
    __shared__ float sfo[256];
    __shared__ float srt[64 * 8];
    __shared__ float red[8][128];
    const int tid = threadIdx.x;
    if (tid < 256) {
        const int b = tid >> 5, j = tid & 31;
        float s = 0.f;
#pragma unroll
        for (int kc = 0; kc < 16; ++kc) s += partials[(j * 16 + kc) * 8 + b];
        sfo[b * 32 + j] = fmaxf(s + f1b[j], 0.f);
    }
    __syncthreads();
    if (tid < 64) {
        const int b = tid >> 3, t = tid & 7;
        const float* f = &sfo[b * 32];
        float th[6];
#pragma unroll
        for (int i = 0; i < 6; ++i) {
            const int o = t * 6 + i;
            float s = bias[o];
            const float* wr = w + o * 32;
#pragma unroll
            for (int k = 0; k < 32; ++k) s = fmaf(f[k], wr[k], s);
            th[i] = tanhf(s);
        }
        float s0, c0, s1, c1, s2, c2;
        sincosf(PI_F * th[0], &s0, &c0);
        sincosf(PI_F * th[1], &s1, &c1);
        sincosf(PI_F * th[2], &s2, &c2);
        const float R00 = c0 * c1, R10 = s0 * c1, R20 = -s1;
        const float R01 = -s0 * c2 + c0 * s1 * s2;
        const float R11 =  c0 * c2 + s0 * s1 * s2;
        const float R21 =  c1 * s2;
        const float T0 = th[3] * 128.f + 64.f - (64.f * R00 + 64.f * R10 + 4.f * R20);
        const float T1 = th[4] * 128.f + 64.f - (64.f * R01 + 64.f * R11 + 4.f * R21);
        float* o = srt + tid * 8;
        o[0] = R00; o[1] = R10; o[2] = R20; o[3] = T0;
        o[4] = R01; o[5] = R11; o[6] = R21; o[7] = T1;
        float* og = rt + tid * 8;
        og[0] = R00; og[1] = R10; og[2] = R20; og[3] = T0;
        og[4] = R01; og[5] = R11; og[6] = R21; og[7] = T1;
    }
    __syncthreads();
    const int b = tid >> 7, p = tid & 127;
    float nrm = 0.f;
    if (p < 100) {
        const float* pp = pos + ((size_t)b * 100 + p) * 3;
        const float p0 = pp[0], p1 = pp[1], p2 = pp[2];
        int i0 = (int)rintf(p0); i0 = i0 < 0 ? 0 : (i0 > 127 ? 127 : i0);
        int i1 = (int)rintf(p1); i1 = i1 < 0 ? 0 : (i1 > 127 ? 127 : i1);
        int i2 = (int)rintf(p2); i2 = i2 < 0 ? 0 : (i2 > 7 ? 7 : i2);
        const float gi = (float)i0, gj = (float)i1, gk = (float)i2;
        const float tsx[8] = {32.f, 32.f, 96.f, 96.f, 32.f, 96.f, 64.f, 64.f};
        const float tsy[8] = {32.f, 96.f, 32.f, 96.f, 64.f, 64.f, 32.f, 96.f};
        float u0 = 0.f, u1 = 0.f, es = 0.f;
#pragma unroll
        for (int t = 0; t < 8; ++t) {
            float dx = gi - tsx[t], dy = gj - tsy[t], dz = gk - 4.f;
            float d = sqrtf(dx * dx + dy * dy + dz * dz);
            float e = expf(-d / 10.f);
            const float* r = srt + (b * 8 + t) * 8;
            float f0 = fmaf(gi, r[0], fmaf(gj, r[1], fmaf(gk, r[2], r[3])));
            float f1 = fmaf(gi, r[4], fmaf(gj, r[5], fmaf(gk, r[6], r[7])));
            u0 = fmaf(e, f0, u0);
            u1 = fmaf(e, f1, u1);
            es += e;
        }
        const float inv = 1.f / es;
        const float nf0 = (u0 * inv) * (1.f / 64.f) - 1.f;
        const float nf1 = (u1 * inv) * (1.f / 64.f) - 1.f;
        const float m0 = 2.f * p0 - (0.5f + 0.5f * nf0) * 127.f;
        const float m1 = 2.f * p1 - (0.5f + 0.5f * nf1) * 127.f;
        const float m2 = 2.f * p2 - 3.5f;
        float* mo = movedOut + ((size_t)b * 100 + p) * 3;
        mo[0] = m0; mo[1] = m1; mo[2] = m2;
        const float* ce = centers + p * 3;
        const float d0 = m0 - ce[0], d1 = m1 - ce[1], d2 = m2 - ce[2];
        nrm = sqrtf(d0 * d0 + d1 * d1 + d2 * d2);
    }
    red[b][p] = nrm;
    __syncthreads();
    for (int s = 64; s > 0; s >>= 1) {
        if (p < s) red[b][p] += red[b][p + s];
        __syncthreads();
    }
    if (p == 0) regOut[b] = red[b][0] * 0.01f;
}

// ---------------- K5: flow field + grid output + trilinear grid-sample (fused) ----------
__global__ __launch_bounds__(256) void k_flow_sample(const float* __restrict__ x,
                                                     const float* __restrict__ rt,
                                                     float* __restrict__ outXt,
                                                     float* __restrict__ outGrid) {
    const int b = blockIdx.y;
    const int l = blockIdx.x * 256 + threadIdx.x;   // voxel index, 131072 per batch
    __shared__ float srt[64];
    __shared__ float sg[768];
    if (threadIdx.x < 64) srt[threadIdx.x] = rt[b * 64 + threadIdx.x];
    __syncthreads();

    const float gi = (float)(l >> 10);
    const float gj = (float)((l >> 3) & 127);
    const float gk = (float)(l & 7);

    const float tsx[8] = {32.f, 32.f, 96.f, 96.f, 32.f, 96.f, 64.f, 64.f};
    const float tsy[8] = {32.f, 96.f, 32.f, 96.f, 64.f, 64.f, 32.f, 96.f};

    float u0 = 0.f, u1 = 0.f, es = 0.f;
#pragma unroll
    for (int t = 0; t < 8; ++t) {
        float dx = gi - tsx[t], dy = gj - tsy[t], dz = gk - 4.f;
        float d = sqrtf(dx * dx + dy * dy + dz * dz);
        float e = expf(-d / 10.f);
        const float4 ra = *reinterpret_cast<const float4*>(&srt[t * 8]);
        const float4 rb = *reinterpret_cast<const float4*>(&srt[t * 8 + 4]);
        float f0 = fmaf(gi, ra.x, fmaf(gj, ra.y, fmaf(gk, ra.z, ra.w)));
        float f1 = fmaf(gi, rb.x, fmaf(gj, rb.y, fmaf(gk, rb.z, rb.w)));
        u0 = fmaf(e, f0, u0);
        u1 = fmaf(e, f1, u1);
        es += e;
    }
    const float inv = 1.f / es;
    const float fs0 = u0 * inv, fs1 = u1 * inv;
    const float nf0 = fs0 * (1.f / 64.f) - 1.f;
    const float nf1 = fs1 * (1.f / 64.f) - 1.f;

    // coalesced grid store via LDS transpose
    sg[threadIdx.x * 3 + 0] = 0.f;
    sg[threadIdx.x * 3 + 1] = nf1;
    sg[threadIdx.x * 3 + 2] = nf0;
    __syncthreads();
    if (threadIdx.x < 192) {
        *reinterpret_cast<float4*>(outGrid + (size_t)b * 393216 + (size_t)blockIdx.x * 768 +
                                   threadIdx.x * 4) = *reinterpret_cast<float4*>(&sg[threadIdx.x * 4]);
    }

    const float iz = fs0 - 0.5f, iy = fs1 - 0.5f;
    const float z0f = floorf(iz), y0f = floorf(iy);
    const float fz = iz - z0f, fy = iy - y0f;
    const int z0 = (int)z0f, y0 = (int)y0f;
    float s0 = 0.f, s1 = 0.f, s2 = 0.f, s3 = 0.f;
    const float* xb = x + (size_t)b * 4 * 131072;
#pragma unroll
    for (int dz = 0; dz < 2; ++dz) {
        const int zc = z0 + dz;
        if (zc < 0 || zc > 127) continue;
        const float wz = dz ? fz : 1.f - fz;
#pragma unroll
        for (int dy = 0; dy < 2; ++dy) {
            const int yc = y0 + dy;
            if (yc < 0 || yc > 127) continue;
            const float wv = wz * (dy ? fy : 1.f - fy) * 0.5f;
            const float* p = xb + ((size_t)zc * 128 + yc) * 8 + 3;
            s0 = fmaf(wv, p[0] + p[1], s0);
            s1 = fmaf(wv, p[131072] + p[131073], s1);
            s2 = fmaf(wv, p[262144] + p[262145], s2);
            s3 = fmaf(wv, p[393216] + p[393217], s3);
        }
    }
    float* o = outXt + (size_t)b * 4 * 131072 + l;
    o[0] = s0; o[131072] = s1; o[262144] = s2; o[393216] = s3;
}

// ---------------- launch ----------------
extern "C" void kernel_launch(void* const* d_in, const int* in_sizes, int n_in,
                              void* d_out, int out_size, void* d_ws, size_t ws_size,
                              hipStream_t stream) {
    const float* x       = (const float*)d_in[0];
    const float* pos     = (const float*)d_in[1];
    const float* centers = (const float*)d_in[2];
    const float* c1w     = (const float*)d_in[3];
    const float* c1b     = (const float*)d_in[4];
    const float* c2w     = (const float*)d_in[5];
    const float* c2b     = (const float*)d_in[6];
    const float* f1w     = (const float*)d_in[7];
    const float* f1b     = (const float*)d_in[8];
    const float* f2w     = (const float*)d_in[9];
    const float* f2b     = (const float*)d_in[10];

    float* out = (float*)d_out;
    float* ws  = (float*)d_ws;

    // workspace layout (floats)
    float* h1       = ws;                      // 8*8*61*61*8   = 1,905,152
    float* h2       = h1 + 1905152;            // 8*10*28*28*8  =   501,760
    float* partials = h2 + 501760;             // 32*16*8       =     4,096
    float* rt       = partials + 4096;         // 8*8*8         =       512

    // output layout (floats): X_t | grid | reg | moved
    float* outXt    = out;                         // 4,194,304
    float* outGrid  = out + 4194304;               // 3,145,728
    float* outReg   = out + 4194304 + 3145728;     // 8
    float* outMoved = outReg + 8;                  // 2,400

    // weight stash in tail of outGrid — fully overwritten by k_flow_sample afterwards
    float* stash = out + 4194304 + 3145728 - 4096;
    float* wt1 = stash;                  // 1568
    float* wt2 = stash + 1568;           // 2400

    k_prep<<<1, 256, 0, stream>>>(c1w, c2w, wt1, wt2);
    k_conv1<<<dim3(256, 8), 256, 0, stream>>>(x, wt1, c1b, h1);
    k_conv2<<<dim3(98, 8), 256, 0, stream>>>(h1, wt2, c2b, h2);
    k_fc1<<<512, 256, 0, stream>>>(h2, f1w, partials);
    k_fc2_moved<<<1, 1024, 0, stream>>>(partials, f1b, f2w, f2b, pos, centers, rt, outMoved, outReg);
    k_flow_sample<<<dim3(512, 8), 256, 0, stream>>>(x, rt, outXt, outGrid);
}

// Round 12
// 95.008 us; speedup vs baseline: 1.2575x; 1.2575x over previous
//
#include <hip/hip_runtime.h>

#define PI_F 3.14159265358979323846f

typedef _Float16 h2t __attribute__((ext_vector_type(2)));
typedef __fp16 fp16x2 __attribute__((ext_vector_type(2)));
typedef unsigned int uint32;

// f16 dot2 with f32 accumulate; weight dword in SGPR (scalar pipe)
__device__ __forceinline__ void dot2(float& d, uint32 v, uint32 w) {
    asm("v_dot2_f32_f16 %0, %1, %2, %0" : "+v"(d) : "v"(v), "s"(w));
}

__device__ __forceinline__ uint32 packh(float a, float b) {   // RNE, for prep
    h2t h = {(_Float16)a, (_Float16)b};
    return __builtin_bit_cast(uint32, h);
}
__device__ __forceinline__ uint32 pkrtz(float a, float b) {   // fast, for staging
    fp16x2 h = __builtin_amdgcn_cvt_pkrtz(a, b);
    return __builtin_bit_cast(uint32, h);
}

// ---------------- K0: pack weights to f16 ic-pairs ----------------
// wt1h[tap*16 + oc*2 + icp] = pack(W1(oc, 2icp, tap), W1(oc, 2icp+1, tap))
// wt2h[tap*40 + oc*4 + d]   = pack(W2(oc, 2d, tap),   W2(oc, 2d+1, tap))
__global__ void k_prep(const float* __restrict__ w1, const float* __restrict__ w2,
                       uint32* __restrict__ wt1h, uint32* __restrict__ wt2h) {
    const int tid = threadIdx.x;
    for (int i = tid; i < 784; i += 256) {
        const int tap = i >> 4, rem = i & 15, oc = rem >> 1, icp = rem & 1;
        wt1h[i] = packh(w1[(oc * 4 + icp * 2) * 49 + tap],
                        w1[(oc * 4 + icp * 2 + 1) * 49 + tap]);
    }
    for (int i = tid; i < 1000; i += 256) {
        const int tap = i / 40, rem = i % 40, oc = rem >> 2, d = rem & 3;
        wt2h[i] = packh(w2[(oc * 8 + 2 * d) * 25 + tap],
                        w2[(oc * 8 + 2 * d + 1) * 25 + tap]);
    }
}

// ---------------- K1: conv1 7x7 (4->8) + maxpool 2x2 + bias + relu ----------------
// x:(8,4,128,128,8) -> h1:(8,8,61,61,8). f16 dot2 over ic-pairs, f32 accum.
// 2048 blocks (8/CU), 256 thr = pp(16) x cp(4) x wq(4, w-pair).
// LDS f16 [14r][15c][8w][4ic] (13440B, single buffer, one barrier).
// Per tap: 1 ds_read_b128 -> 32 dot2. Weights: uniform s_load dwords (SGPR operand).
__global__ __launch_bounds__(256) void k_conv1(const float* __restrict__ x,
                                               const uint32* __restrict__ wt1h,
                                               const float* __restrict__ b1,
                                               float* __restrict__ h1) {
    const int b = blockIdx.y;
    const int ty = blockIdx.x >> 4, tx = blockIdx.x & 15;   // 16 x 16 tiles
    const int py0 = ty * 4, px0 = tx * 4;
    const int iy0 = py0 * 2, ix0 = px0 * 2;

    __shared__ uint32 tin[14 * 15 * 16];   // dword idx = (r*15+c)*16 + w*2 + icp

    const int tid = threadIdx.x;
    const int wq  = tid & 3;               // w-pair {2wq, 2wq+1}
    const int cp  = (tid >> 2) & 3;
    const int cpx = cp & 1, cpy = cp >> 1;
    const int pp  = tid >> 4;
    const int pl  = pp >> 2, pj = pp & 3;

    // staging: 392 slots = 14 rows x 14 cols x 2 w-quads; cvt f32->f16, interleave ic
    const float* xb = x + (size_t)b * 4 * 131072;
    for (int s = tid; s < 392; s += 256) {
        const int r = s / 28, rem = s % 28, c = rem >> 1, wqs = rem & 1;
        const int row = min(iy0 + r, 127), col = min(ix0 + c, 127);
        const float* base = xb + ((size_t)row * 128 + col) * 8 + wqs * 4;
        const float4 f0 = *reinterpret_cast<const float4*>(base);
        const float4 f1 = *reinterpret_cast<const float4*>(base + 131072);
        const float4 f2 = *reinterpret_cast<const float4*>(base + 262144);
        const float4 f3 = *reinterpret_cast<const float4*>(base + 393216);
        const int bi = (r * 15 + c) * 16 + wqs * 8;
        uint2 o0 = make_uint2(pkrtz(f0.x, f1.x), pkrtz(f2.x, f3.x));
        uint2 o1 = make_uint2(pkrtz(f0.y, f1.y), pkrtz(f2.y, f3.y));
        uint2 o2 = make_uint2(pkrtz(f0.z, f1.z), pkrtz(f2.z, f3.z));
        uint2 o3 = make_uint2(pkrtz(f0.w, f1.w), pkrtz(f2.w, f3.w));
        *reinterpret_cast<uint2*>(&tin[bi + 0]) = o0;
        *reinterpret_cast<uint2*>(&tin[bi + 2]) = o1;
        *reinterpret_cast<uint2*>(&tin[bi + 4]) = o2;
        *reinterpret_cast<uint2*>(&tin[bi + 6]) = o3;
    }
    __syncthreads();

    float acc[8][2] = {};
    const int rowb = 2 * pl + cpy, colb = 2 * pj + cpx;

    for (int kd = 0; kd < 7; ++kd) {
        const int rbase = (rowb + kd) * 15 + colb;
#pragma unroll
        for (int kh = 0; kh < 7; ++kh) {
            const uint4 v = *reinterpret_cast<const uint4*>(&tin[(rbase + kh) * 16 + wq * 4]);
            const uint32* wt = wt1h + (kd * 7 + kh) * 16;
#pragma unroll
            for (int oc = 0; oc < 8; ++oc) {
                const uint32 wA = wt[oc * 2], wB = wt[oc * 2 + 1];
                dot2(acc[oc][0], v.x, wA);
                dot2(acc[oc][0], v.y, wB);
                dot2(acc[oc][1], v.z, wA);
                dot2(acc[oc][1], v.w, wB);
            }
        }
    }

    // pool: cpx = lane bit2 (shfl_xor 4), cpy = bit3 (shfl_xor 8)
    const int pi = py0 + pl, pjg = px0 + pj;
    const bool doStore = (cp == 0) && (pi < 61) && (pjg < 61);
#pragma unroll
    for (int oc = 0; oc < 8; ++oc) {
        float a0 = acc[oc][0], a1 = acc[oc][1];
        a0 = fmaxf(a0, __shfl_xor(a0, 4)); a0 = fmaxf(a0, __shfl_xor(a0, 8));
        a1 = fmaxf(a1, __shfl_xor(a1, 4)); a1 = fmaxf(a1, __shfl_xor(a1, 8));
        if (doStore) {
            const float bb = b1[oc];
            *reinterpret_cast<float2*>(
                h1 + ((((size_t)b * 8 + oc) * 61 + pi) * 61 + pjg) * 8 + 2 * wq) =
                make_float2(fmaxf(a0 + bb, 0.f), fmaxf(a1 + bb, 0.f));
        }
    }
}

// ---------------- K2: conv2 5x5 (8->10) + maxpool 2x2 + bias + relu ----------------
// h1:(8,8,61,61,8) -> h2:(8,10,28,28,8). f16 dot2 over 4 ic-pairs, f32 accum.
// 784 blocks, 256 thr = pp(8) x cp(4) x w(8). Full K per thread (no cross-wave reduce).
// LDS f16 [8r][12c][8w][8ic] (12288B). Per tap: 1 ds_read_b128 -> 40 dot2.
__global__ __launch_bounds__(256) void k_conv2(const float* __restrict__ h1,
                                               const uint32* __restrict__ wt2h,
                                               const float* __restrict__ b2,
                                               float* __restrict__ h2) {
    const int b = blockIdx.y;
    const int ty = blockIdx.x / 7, tx = blockIdx.x % 7;    // 14 x 7 tiles
    const int py0 = ty * 2, px0 = tx * 4;
    const int iy0 = py0 * 2, ix0 = px0 * 2;

    __shared__ uint32 tin[8 * 12 * 32];    // dword idx = ((r*12+c)*8 + w)*4 + d

    const int tid = threadIdx.x;
    const int w   = tid & 7;
    const int cp  = (tid >> 3) & 3;
    const int cpx = cp & 1, cpy = cp >> 1;
    const int pp  = tid >> 5;              // 0..7
    const int pl  = pp >> 2, pj = pp & 3;

    const float* hb = h1 + (size_t)b * 8 * 29768;
    if (tid < 192) {   // 8 rows x 12 cols x 2 w-quads
        const int r = tid / 24, rem = tid % 24, c = rem >> 1, wqs = rem & 1;
        const float* base = hb + ((size_t)(iy0 + r) * 61 + ix0 + c) * 8 + wqs * 4;
        const float4 f0 = *reinterpret_cast<const float4*>(base);
        const float4 f1 = *reinterpret_cast<const float4*>(base + 29768);
        const float4 f2 = *reinterpret_cast<const float4*>(base + 2 * 29768);
        const float4 f3 = *reinterpret_cast<const float4*>(base + 3 * 29768);
        const float4 f4 = *reinterpret_cast<const float4*>(base + 4 * 29768);
        const float4 f5 = *reinterpret_cast<const float4*>(base + 5 * 29768);
        const float4 f6 = *reinterpret_cast<const float4*>(base + 6 * 29768);
        const float4 f7 = *reinterpret_cast<const float4*>(base + 7 * 29768);
        const int bi = ((r * 12 + c) * 8 + wqs * 4) * 4;
        uint4 ox = make_uint4(pkrtz(f0.x, f1.x), pkrtz(f2.x, f3.x), pkrtz(f4.x, f5.x), pkrtz(f6.x, f7.x));
        uint4 oy = make_uint4(pkrtz(f0.y, f1.y), pkrtz(f2.y, f3.y), pkrtz(f4.y, f5.y), pkrtz(f6.y, f7.y));
        uint4 oz = make_uint4(pkrtz(f0.z, f1.z), pkrtz(f2.z, f3.z), pkrtz(f4.z, f5.z), pkrtz(f6.z, f7.z));
        uint4 ow = make_uint4(pkrtz(f0.w, f1.w), pkrtz(f2.w, f3.w), pkrtz(f4.w, f5.w), pkrtz(f6.w, f7.w));
        *reinterpret_cast<uint4*>(&tin[bi +  0]) = ox;
        *reinterpret_cast<uint4*>(&tin[bi +  4]) = oy;
        *reinterpret_cast<uint4*>(&tin[bi +  8]) = oz;
        *reinterpret_cast<uint4*>(&tin[bi + 12]) = ow;
    }
    __syncthreads();

    float acc[10] = {};
    const int cy = 2 * pl + cpy, cx = 2 * pj + cpx;

    for (int kd = 0; kd < 5; ++kd) {
        const int rbase = (cy + kd) * 12 + cx;
#pragma unroll
        for (int kh = 0; kh < 5; ++kh) {
            const uint4 v = *reinterpret_cast<const uint4*>(&tin[((rbase + kh) * 8 + w) * 4]);
            const uint32* wt = wt2h + (kd * 5 + kh) * 40;
#pragma unroll
            for (int oc = 0; oc < 10; ++oc) {
                dot2(acc[oc], v.x, wt[oc * 4]);
                dot2(acc[oc], v.y, wt[oc * 4 + 1]);
                dot2(acc[oc], v.z, wt[oc * 4 + 2]);
                dot2(acc[oc], v.w, wt[oc * 4 + 3]);
            }
        }
    }

    // pool: cpx = lane bit3 (shfl_xor 8), cpy = bit4 (shfl_xor 16)
    const int pi = py0 + pl, pjg = px0 + pj;   // always < 28
    const bool doStore = (cp == 0);
#pragma unroll
    for (int oc = 0; oc < 10; ++oc) {
        float a = acc[oc];
        a = fmaxf(a, __shfl_xor(a, 8)); a = fmaxf(a, __shfl_xor(a, 16));
        if (doStore)
            h2[((((size_t)b * 10 + oc) * 28 + pi) * 28 + pjg) * 8 + w] =
                fmaxf(a + b2[oc], 0.f);
    }
}

// ---------------- K3: fc1 (62720 -> 32), split-K, partials to ws ----------------
__global__ __launch_bounds__(256) void k_fc1(const float* __restrict__ feat,
                                             const float* __restrict__ w,
                                             float* __restrict__ partials) {
    const int j = blockIdx.x >> 4;
    const int kc = blockIdx.x & 15;
    const int k0 = kc * 3920;
    const float4* w4 = reinterpret_cast<const float4*>(w + (size_t)j * 62720 + k0);
    float acc[8];
#pragma unroll
    for (int b = 0; b < 8; ++b) acc[b] = 0.f;
    for (int i = threadIdx.x; i < 980; i += 256) {
        const float4 wv = w4[i];
#pragma unroll
        for (int b = 0; b < 8; ++b) {
            const float4 fv = *reinterpret_cast<const float4*>(feat + (size_t)b * 62720 + k0 + i * 4);
            acc[b] = fmaf(wv.x, fv.x, fmaf(wv.y, fv.y, fmaf(wv.z, fv.z, fmaf(wv.w, fv.w, acc[b]))));
        }
    }
#pragma unroll
    for (int b = 0; b < 8; ++b)
#pragma unroll
        for (int off = 32; off > 0; off >>= 1) acc[b] += __shfl_down(acc[b], off);
    __shared__ float red[4][8];
    const int wave = threadIdx.x >> 6;
    if ((threadIdx.x & 63) == 0)
#pragma unroll
        for (int b = 0; b < 8; ++b) red[wave][b] = acc[b];
    __syncthreads();
    if (threadIdx.x < 8) {
        partials[(j * 16 + kc) * 8 + threadIdx.x] =
            red[0][threadIdx.x] + red[1][threadIdx.x] + red[2][threadIdx.x] + red[3][threadIdx.x];
    }
}

// ---------------- K4: fc1-reduce + bias/relu + fc2 + tanh + rigid + moved/reg ----------
__global__ __launch_bounds__(1024) void k_fc2_moved(const float* __restrict__ partials,
                                                    const float* __restrict__ f1b,
                                                    const float* __restrict__ w,
                                                    const float* __restrict__ bias,
                                                    const float* __restrict__ pos,
                                                    const float* __restrict__ centers,
                                                    float* __restrict__ rt,
                                                    float* __restrict__ movedOut,
                                                    float* __restrict__ regOut) {
    __shared__ float sfo[256];
    __shared__ float srt[64 * 8];
    __shared__ float red[8][128];
    const int tid = threadIdx.x;
    if (tid < 256) {
        const int b = tid >> 5, j = tid & 31;
        float s = 0.f;
#pragma unroll
        for (int kc = 0; kc < 16; ++kc) s += partials[(j * 16 + kc) * 8 + b];
        sfo[b * 32 + j] = fmaxf(s + f1b[j], 0.f);
    }
    __syncthreads();
    if (tid < 64) {
        const int b = tid >> 3, t = tid & 7;
        const float* f = &sfo[b * 32];
        float th[6];
#pragma unroll
        for (int i = 0; i < 6; ++i) {
            const int o = t * 6 + i;
            float s = bias[o];
            const float* wr = w + o * 32;
#pragma unroll
            for (int k = 0; k < 32; ++k) s = fmaf(f[k], wr[k], s);
            th[i] = tanhf(s);
        }
        float s0, c0, s1, c1, s2, c2;
        sincosf(PI_F * th[0], &s0, &c0);
        sincosf(PI_F * th[1], &s1, &c1);
        sincosf(PI_F * th[2], &s2, &c2);
        const float R00 = c0 * c1, R10 = s0 * c1, R20 = -s1;
        const float R01 = -s0 * c2 + c0 * s1 * s2;
        const float R11 =  c0 * c2 + s0 * s1 * s2;
        const float R21 =  c1 * s2;
        const float T0 = th[3] * 128.f + 64.f - (64.f * R00 + 64.f * R10 + 4.f * R20);
        const float T1 = th[4] * 128.f + 64.f - (64.f * R01 + 64.f * R11 + 4.f * R21);
        float* o = srt + tid * 8;
        o[0] = R00; o[1] = R10; o[2] = R20; o[3] = T0;
        o[4] = R01; o[5] = R11; o[6] = R21; o[7] = T1;
        float* og = rt + tid * 8;
        og[0] = R00; og[1] = R10; og[2] = R20; og[3] = T0;
        og[4] = R01; og[5] = R11; og[6] = R21; og[7] = T1;
    }
    __syncthreads();
    const int b = tid >> 7, p = tid & 127;
    float nrm = 0.f;
    if (p < 100) {
        const float* pp = pos + ((size_t)b * 100 + p) * 3;
        const float p0 = pp[0], p1 = pp[1], p2 = pp[2];
        int i0 = (int)rintf(p0); i0 = i0 < 0 ? 0 : (i0 > 127 ? 127 : i0);
        int i1 = (int)rintf(p1); i1 = i1 < 0 ? 0 : (i1 > 127 ? 127 : i1);
        int i2 = (int)rintf(p2); i2 = i2 < 0 ? 0 : (i2 > 7 ? 7 : i2);
        const float gi = (float)i0, gj = (float)i1, gk = (float)i2;
        const float tsx[8] = {32.f, 32.f, 96.f, 96.f, 32.f, 96.f, 64.f, 64.f};
        const float tsy[8] = {32.f, 96.f, 32.f, 96.f, 64.f, 64.f, 32.f, 96.f};
        float u0 = 0.f, u1 = 0.f, es = 0.f;
#pragma unroll
        for (int t = 0; t < 8; ++t) {
            float dx = gi - tsx[t], dy = gj - tsy[t], dz = gk - 4.f;
            float d = sqrtf(dx * dx + dy * dy + dz * dz);
            float e = expf(-d / 10.f);
            const float* r = srt + (b * 8 + t) * 8;
            float f0 = fmaf(gi, r[0], fmaf(gj, r[1], fmaf(gk, r[2], r[3])));
            float f1 = fmaf(gi, r[4], fmaf(gj, r[5], fmaf(gk, r[6], r[7])));
            u0 = fmaf(e, f0, u0);
            u1 = fmaf(e, f1, u1);
            es += e;
        }
        const float inv = 1.f / es;
        const float nf0 = (u0 * inv) * (1.f / 64.f) - 1.f;
        const float nf1 = (u1 * inv) * (1.f / 64.f) - 1.f;
        const float m0 = 2.f * p0 - (0.5f + 0.5f * nf0) * 127.f;
        const float m1 = 2.f * p1 - (0.5f + 0.5f * nf1) * 127.f;
        const float m2 = 2.f * p2 - 3.5f;
        float* mo = movedOut + ((size_t)b * 100 + p) * 3;
        mo[0] = m0; mo[1] = m1; mo[2] = m2;
        const float* ce = centers + p * 3;
        const float d0 = m0 - ce[0], d1 = m1 - ce[1], d2 = m2 - ce[2];
        nrm = sqrtf(d0 * d0 + d1 * d1 + d2 * d2);
    }
    red[b][p] = nrm;
    __syncthreads();
    for (int s = 64; s > 0; s >>= 1) {
        if (p < s) red[b][p] += red[b][p + s];
        __syncthreads();
    }
    if (p == 0) regOut[b] = red[b][0] * 0.01f;
}

// ---------------- K5: flow field + grid output + trilinear grid-sample (fused) ----------
__global__ __launch_bounds__(256) void k_flow_sample(const float* __restrict__ x,
                                                     const float* __restrict__ rt,
                                                     float* __restrict__ outXt,
                                                     float* __restrict__ outGrid) {
    const int b = blockIdx.y;
    const int l = blockIdx.x * 256 + threadIdx.x;   // voxel index, 131072 per batch
    __shared__ float srt[64];
    __shared__ float sg[768];
    if (threadIdx.x < 64) srt[threadIdx.x] = rt[b * 64 + threadIdx.x];
    __syncthreads();

    const float gi = (float)(l >> 10);
    const float gj = (float)((l >> 3) & 127);
    const float gk = (float)(l & 7);

    const float tsx[8] = {32.f, 32.f, 96.f, 96.f, 32.f, 96.f, 64.f, 64.f};
    const float tsy[8] = {32.f, 96.f, 32.f, 96.f, 64.f, 64.f, 32.f, 96.f};

    float u0 = 0.f, u1 = 0.f, es = 0.f;
#pragma unroll
    for (int t = 0; t < 8; ++t) {
        float dx = gi - tsx[t], dy = gj - tsy[t], dz = gk - 4.f;
        float d = sqrtf(dx * dx + dy * dy + dz * dz);
        float e = expf(-d / 10.f);
        const float4 ra = *reinterpret_cast<const float4*>(&srt[t * 8]);
        const float4 rb = *reinterpret_cast<const float4*>(&srt[t * 8 + 4]);
        float f0 = fmaf(gi, ra.x, fmaf(gj, ra.y, fmaf(gk, ra.z, ra.w)));
        float f1 = fmaf(gi, rb.x, fmaf(gj, rb.y, fmaf(gk, rb.z, rb.w)));
        u0 = fmaf(e, f0, u0);
        u1 = fmaf(e, f1, u1);
        es += e;
    }
    const float inv = 1.f / es;
    const float fs0 = u0 * inv, fs1 = u1 * inv;
    const float nf0 = fs0 * (1.f / 64.f) - 1.f;
    const float nf1 = fs1 * (1.f / 64.f) - 1.f;

    // coalesced grid store via LDS transpose
    sg[threadIdx.x * 3 + 0] = 0.f;
    sg[threadIdx.x * 3 + 1] = nf1;
    sg[threadIdx.x * 3 + 2] = nf0;
    __syncthreads();
    if (threadIdx.x < 192) {
        *reinterpret_cast<float4*>(outGrid + (size_t)b * 393216 + (size_t)blockIdx.x * 768 +
                                   threadIdx.x * 4) = *reinterpret_cast<float4*>(&sg[threadIdx.x * 4]);
    }

    const float iz = fs0 - 0.5f, iy = fs1 - 0.5f;
    const float z0f = floorf(iz), y0f = floorf(iy);
    const float fz = iz - z0f, fy = iy - y0f;
    const int z0 = (int)z0f, y0 = (int)y0f;
    float s0 = 0.f, s1 = 0.f, s2 = 0.f, s3 = 0.f;
    const float* xb = x + (size_t)b * 4 * 131072;
#pragma unroll
    for (int dz = 0; dz < 2; ++dz) {
        const int zc = z0 + dz;
        if (zc < 0 || zc > 127) continue;
        const float wz = dz ? fz : 1.f - fz;
#pragma unroll
        for (int dy = 0; dy < 2; ++dy) {
            const int yc = y0 + dy;
            if (yc < 0 || yc > 127) continue;
            const float wv = wz * (dy ? fy : 1.f - fy) * 0.5f;
            const float* p = xb + ((size_t)zc * 128 + yc) * 8 + 3;
            s0 = fmaf(wv, p[0] + p[1], s0);
            s1 = fmaf(wv, p[131072] + p[131073], s1);
            s2 = fmaf(wv, p[262144] + p[262145], s2);
            s3 = fmaf(wv, p[393216] + p[393217], s3);
        }
    }
    float* o = outXt + (size_t)b * 4 * 131072 + l;
    o[0] = s0; o[131072] = s1; o[262144] = s2; o[393216] = s3;
}

// ---------------- launch ----------------
extern "C" void kernel_launch(void* const* d_in, const int* in_sizes, int n_in,
                              void* d_out, int out_size, void* d_ws, size_t ws_size,
                              hipStream_t stream) {
    const float* x       = (const float*)d_in[0];
    const float* pos     = (const float*)d_in[1];
    const float* centers = (const float*)d_in[2];
    const float* c1w     = (const float*)d_in[3];
    const float* c1b     = (const float*)d_in[4];
    const float* c2w     = (const float*)d_in[5];
    const float* c2b     = (const float*)d_in[6];
    const float* f1w     = (const float*)d_in[7];
    const float* f1b     = (const float*)d_in[8];
    const float* f2w     = (const float*)d_in[9];
    const float* f2b     = (const float*)d_in[10];

    float* out = (float*)d_out;
    float* ws  = (float*)d_ws;

    // workspace layout (floats)
    float* h1       = ws;                      // 8*8*61*61*8   = 1,905,152
    float* h2       = h1 + 1905152;            // 8*10*28*28*8  =   501,760
    float* partials = h2 + 501760;             // 32*16*8       =     4,096
    float* rt       = partials + 4096;         // 8*8*8         =       512

    // output layout (floats): X_t | grid | reg | moved
    float* outXt    = out;                         // 4,194,304
    float* outGrid  = out + 4194304;               // 3,145,728
    float* outReg   = out + 4194304 + 3145728;     // 8
    float* outMoved = outReg + 8;                  // 2,400

    // f16 weight stash in tail of outGrid — fully overwritten by k_flow_sample afterwards
    uint32* wt1h = (uint32*)(out + 4194304 + 3145728 - 4096);   // 784 dwords
    uint32* wt2h = wt1h + 784;                                   // 1000 dwords

    k_prep<<<1, 256, 0, stream>>>(c1w, c2w, wt1h, wt2h);
    k_conv1<<<dim3(256, 8), 256, 0, stream>>>(x, wt1h, c1b, h1);
    k_conv2<<<dim3(98, 8), 256, 0, stream>>>(h1, wt2h, c2b, h2);
    k_fc1<<<512, 256, 0, stream>>>(h2, f1w, partials);
    k_fc2_moved<<<1, 1024, 0, stream>>>(partials, f1b, f2w, f2b, pos, centers, rt, outMoved, outReg);
    k_flow_sample<<<dim3(512, 8), 256, 0, stream>>>(x, rt, outXt, outGrid);
}

// Round 13
// 87.779 us; speedup vs baseline: 1.3611x; 1.0824x over previous
//
#include <hip/hip_runtime.h>

#define PI_F 3.14159265358979323846f

typedef _Float16 h2t __attribute__((ext_vector_type(2)));
typedef __fp16 fp16x2 __attribute__((ext_vector_type(2)));
typedef _Float16 f16x8 __attribute__((ext_vector_type(8)));
typedef float f32x4 __attribute__((ext_vector_type(4)));
typedef unsigned int uint32;

// f16 dot2 with f32 accumulate; weight dword in SGPR (scalar pipe)
__device__ __forceinline__ void dot2(float& d, uint32 v, uint32 w) {
    asm("v_dot2_f32_f16 %0, %1, %2, %0" : "+v"(d) : "v"(v), "s"(w));
}

__device__ __forceinline__ uint32 packh(float a, float b) {   // RNE, for prep
    h2t h = {(_Float16)a, (_Float16)b};
    return __builtin_bit_cast(uint32, h);
}
__device__ __forceinline__ uint32 pkrtz(float a, float b) {   // fast, for staging
    fp16x2 h = __builtin_amdgcn_cvt_pkrtz(a, b);
    return __builtin_bit_cast(uint32, h);
}

// ---------------- K0: pack weights ----------------
// wt1m: MFMA B-fragments for conv1. Slot (ks,c,oc,h,icp):
//   wt1m[((ks*4+c)*16+oc)*4 + h*2 + icp] = pack(W1[oc][2icp][tap], W1[oc][2icp+1][tap]),
//   tap = 8*ks + c + 4*h, zero if tap>=49 or oc>=8.    (1792 dwords)
// wt2h[tap*40 + oc*4 + d] = pack(W2(oc,2d,tap), W2(oc,2d+1,tap))   (1000 dwords)
__global__ void k_prep(const float* __restrict__ w1, const float* __restrict__ w2,
                       uint32* __restrict__ wt1m, uint32* __restrict__ wt2h) {
    const int tid = threadIdx.x;
    for (int i = tid; i < 1792; i += 256) {
        const int idx4 = i >> 2, rem = i & 3;
        const int h = rem >> 1, icp = rem & 1;
        const int oc = idx4 & 15, kc = idx4 >> 4;
        const int ks = kc >> 2, c = kc & 3;
        const int tap = 8 * ks + c + 4 * h;
        uint32 v = 0;
        if (tap < 49 && oc < 8)
            v = packh(w1[(oc * 4 + 2 * icp) * 49 + tap],
                      w1[(oc * 4 + 2 * icp + 1) * 49 + tap]);
        wt1m[i] = v;
    }
    for (int i = tid; i < 1000; i += 256) {
        const int tap = i / 40, rem = i % 40, oc = rem >> 2, d = rem & 3;
        wt2h[i] = packh(w2[(oc * 8 + 2 * d) * 25 + tap],
                        w2[(oc * 8 + 2 * d + 1) * 25 + tap]);
    }
}

// ---------------- K1: conv1 via MFMA 16x16x32_f16 ----------------
// x:(8,4,128,128,8) -> h1:(8,8,61,61,8).
// Implicit GEMM: N=oc(8/16), K=(tap,ic) 7 steps x 32, M=4 pooled x 4 convpos (per w).
// Per wave (=pooled row pl): 8 w-tiles x 7 K-steps = 56 mfma; A = 2 ds_read_b64/mfma;
// B preloaded (28 VGPR). Pool = in-lane max over 4 C-regs (C: col=oc, row=4q+cp).
__global__ __launch_bounds__(256) void k_conv1(const float* __restrict__ x,
                                               const uint32* __restrict__ wt1m,
                                               const float* __restrict__ b1,
                                               float* __restrict__ h1) {
    const int b = blockIdx.y;
    const int ty = blockIdx.x >> 4, tx = blockIdx.x & 15;   // 16 x 16 tiles
    const int py0 = ty * 4, px0 = tx * 4;
    const int iy0 = py0 * 2, ix0 = px0 * 2;

    __shared__ uint32 tin[14 * 15 * 16];   // dword idx = (r*15+c)*16 + w*2 + icp

    const int tid = threadIdx.x;

    // staging: identical to R12 — f16 [14r][15c][8w][4ic]
    const float* xb = x + (size_t)b * 4 * 131072;
    for (int s = tid; s < 392; s += 256) {
        const int r = s / 28, rem = s % 28, c = rem >> 1, wqs = rem & 1;
        const int row = min(iy0 + r, 127), col = min(ix0 + c, 127);
        const float* base = xb + ((size_t)row * 128 + col) * 8 + wqs * 4;
        const float4 f0 = *reinterpret_cast<const float4*>(base);
        const float4 f1 = *reinterpret_cast<const float4*>(base + 131072);
        const float4 f2 = *reinterpret_cast<const float4*>(base + 262144);
        const float4 f3 = *reinterpret_cast<const float4*>(base + 393216);
        const int bi = (r * 15 + c) * 16 + wqs * 8;
        *reinterpret_cast<uint2*>(&tin[bi + 0]) = make_uint2(pkrtz(f0.x, f1.x), pkrtz(f2.x, f3.x));
        *reinterpret_cast<uint2*>(&tin[bi + 2]) = make_uint2(pkrtz(f0.y, f1.y), pkrtz(f2.y, f3.y));
        *reinterpret_cast<uint2*>(&tin[bi + 4]) = make_uint2(pkrtz(f0.z, f1.z), pkrtz(f2.z, f3.z));
        *reinterpret_cast<uint2*>(&tin[bi + 6]) = make_uint2(pkrtz(f0.w, f1.w), pkrtz(f2.w, f3.w));
    }

    const int lane = tid & 63;
    const int wv   = tid >> 6;         // wave id = pooled row pl (0..3)
    const int kc   = lane >> 4;        // K-chunk 0..3
    const int arow = lane & 15;        // A-row = 4*q + cp
    const int q    = arow >> 2, cp = arow & 3;
    const int cpy  = cp >> 1,  cpx = cp & 1;

    // preload B fragments (uniform-coalesced global loads; vmcnt path)
    f16x8 Bf[7];
#pragma unroll
    for (int ks = 0; ks < 7; ++ks) {
        const uint4 t = *reinterpret_cast<const uint4*>(wt1m + (ks * 64 + lane) * 4);
        Bf[ks] = __builtin_bit_cast(f16x8, t);
    }

    // per-lane A offsets (dword index at w=0) for both K-halves of each K-step
    int offs[7][2];
#pragma unroll
    for (int ks = 0; ks < 7; ++ks) {
#pragma unroll
        for (int h = 0; h < 2; ++h) {
            int tap = 8 * ks + kc + 4 * h;
            if (tap > 48) tap = 48;            // B is zero there; clamp keeps read in-bounds
            const int kd = tap / 7, kh = tap % 7;
            const int y = 2 * wv + cpy + kd;   // <= 13
            const int xq = 2 * q + cpx + kh;   // <= 13
            offs[ks][h] = (y * 15 + xq) * 16;
        }
    }

    __syncthreads();

    f32x4 acc[8];
#pragma unroll
    for (int w = 0; w < 8; ++w) acc[w] = (f32x4)(0.f);

#pragma unroll
    for (int w = 0; w < 8; ++w) {
#pragma unroll
        for (int ks = 0; ks < 7; ++ks) {
            const uint2 lo = *reinterpret_cast<const uint2*>(&tin[offs[ks][0] + w * 2]);
            const uint2 hi = *reinterpret_cast<const uint2*>(&tin[offs[ks][1] + w * 2]);
            const uint4 a4 = make_uint4(lo.x, lo.y, hi.x, hi.y);
            acc[w] = __builtin_amdgcn_mfma_f32_16x16x32_f16(
                __builtin_bit_cast(f16x8, a4), Bf[ks], acc[w], 0, 0, 0);
        }
    }

    // epilogue: pool over 4 C-regs (conv quad), bias+relu, store
    const int oc = lane & 15, qo = lane >> 4;
    const int pi = py0 + wv, pjg = px0 + qo;
    if (oc < 8 && pi < 61 && pjg < 61) {
        const float bb = b1[oc];
        float vals[8];
#pragma unroll
        for (int w = 0; w < 8; ++w) {
            const float m = fmaxf(fmaxf(acc[w][0], acc[w][1]), fmaxf(acc[w][2], acc[w][3]));
            vals[w] = fmaxf(m + bb, 0.f);
        }
        float* base = h1 + ((((size_t)b * 8 + oc) * 61 + pi) * 61 + pjg) * 8;
        *reinterpret_cast<float4*>(base)     = make_float4(vals[0], vals[1], vals[2], vals[3]);
        *reinterpret_cast<float4*>(base + 4) = make_float4(vals[4], vals[5], vals[6], vals[7]);
    }
}

// ---------------- K2: conv2 5x5 (8->10) + maxpool 2x2 + bias + relu (f16 dot2) --------
__global__ __launch_bounds__(256) void k_conv2(const float* __restrict__ h1,
                                               const uint32* __restrict__ wt2h,
                                               const float* __restrict__ b2,
                                               float* __restrict__ h2) {
    const int b = blockIdx.y;
    const int ty = blockIdx.x / 7, tx = blockIdx.x % 7;    // 14 x 7 tiles
    const int py0 = ty * 2, px0 = tx * 4;
    const int iy0 = py0 * 2, ix0 = px0 * 2;

    __shared__ uint32 tin[8 * 12 * 32];    // dword idx = ((r*12+c)*8 + w)*4 + d

    const int tid = threadIdx.x;
    const int w   = tid & 7;
    const int cp  = (tid >> 3) & 3;
    const int cpx = cp & 1, cpy = cp >> 1;
    const int pp  = tid >> 5;              // 0..7
    const int pl  = pp >> 2, pj = pp & 3;

    const float* hb = h1 + (size_t)b * 8 * 29768;
    if (tid < 192) {   // 8 rows x 12 cols x 2 w-quads
        const int r = tid / 24, rem = tid % 24, c = rem >> 1, wqs = rem & 1;
        const float* base = hb + ((size_t)(iy0 + r) * 61 + ix0 + c) * 8 + wqs * 4;
        const float4 f0 = *reinterpret_cast<const float4*>(base);
        const float4 f1 = *reinterpret_cast<const float4*>(base + 29768);
        const float4 f2 = *reinterpret_cast<const float4*>(base + 2 * 29768);
        const float4 f3 = *reinterpret_cast<const float4*>(base + 3 * 29768);
        const float4 f4 = *reinterpret_cast<const float4*>(base + 4 * 29768);
        const float4 f5 = *reinterpret_cast<const float4*>(base + 5 * 29768);
        const float4 f6 = *reinterpret_cast<const float4*>(base + 6 * 29768);
        const float4 f7 = *reinterpret_cast<const float4*>(base + 7 * 29768);
        const int bi = ((r * 12 + c) * 8 + wqs * 4) * 4;
        *reinterpret_cast<uint4*>(&tin[bi +  0]) = make_uint4(pkrtz(f0.x, f1.x), pkrtz(f2.x, f3.x), pkrtz(f4.x, f5.x), pkrtz(f6.x, f7.x));
        *reinterpret_cast<uint4*>(&tin[bi +  4]) = make_uint4(pkrtz(f0.y, f1.y), pkrtz(f2.y, f3.y), pkrtz(f4.y, f5.y), pkrtz(f6.y, f7.y));
        *reinterpret_cast<uint4*>(&tin[bi +  8]) = make_uint4(pkrtz(f0.z, f1.z), pkrtz(f2.z, f3.z), pkrtz(f4.z, f5.z), pkrtz(f6.z, f7.z));
        *reinterpret_cast<uint4*>(&tin[bi + 12]) = make_uint4(pkrtz(f0.w, f1.w), pkrtz(f2.w, f3.w), pkrtz(f4.w, f5.w), pkrtz(f6.w, f7.w));
    }
    __syncthreads();

    float acc[10] = {};
    const int cy = 2 * pl + cpy, cx = 2 * pj + cpx;

    for (int kd = 0; kd < 5; ++kd) {
        const int rbase = (cy + kd) * 12 + cx;
#pragma unroll
        for (int kh = 0; kh < 5; ++kh) {
            const uint4 v = *reinterpret_cast<const uint4*>(&tin[((rbase + kh) * 8 + w) * 4]);
            const uint32* wt = wt2h + (kd * 5 + kh) * 40;
#pragma unroll
            for (int oc = 0; oc < 10; ++oc) {
                dot2(acc[oc], v.x, wt[oc * 4]);
                dot2(acc[oc], v.y, wt[oc * 4 + 1]);
                dot2(acc[oc], v.z, wt[oc * 4 + 2]);
                dot2(acc[oc], v.w, wt[oc * 4 + 3]);
            }
        }
    }

    const int pi = py0 + pl, pjg = px0 + pj;   // always < 28
    const bool doStore = (cp == 0);
#pragma unroll
    for (int oc = 0; oc < 10; ++oc) {
        float a = acc[oc];
        a = fmaxf(a, __shfl_xor(a, 8)); a = fmaxf(a, __shfl_xor(a, 16));
        if (doStore)
            h2[((((size_t)b * 10 + oc) * 28 + pi) * 28 + pjg) * 8 + w] =
                fmaxf(a + b2[oc], 0.f);
    }
}

// ---------------- K3: fc1 (62720 -> 32), split-K, partials to ws ----------------
__global__ __launch_bounds__(256) void k_fc1(const float* __restrict__ feat,
                                             const float* __restrict__ w,
                                             float* __restrict__ partials) {
    const int j = blockIdx.x >> 4;
    const int kc = blockIdx.x & 15;
    const int k0 = kc * 3920;
    const float4* w4 = reinterpret_cast<const float4*>(w + (size_t)j * 62720 + k0);
    float acc[8];
#pragma unroll
    for (int b = 0; b < 8; ++b) acc[b] = 0.f;
    for (int i = threadIdx.x; i < 980; i += 256) {
        const float4 wv = w4[i];
#pragma unroll
        for (int b = 0; b < 8; ++b) {
            const float4 fv = *reinterpret_cast<const float4*>(feat + (size_t)b * 62720 + k0 + i * 4);
            acc[b] = fmaf(wv.x, fv.x, fmaf(wv.y, fv.y, fmaf(wv.z, fv.z, fmaf(wv.w, fv.w, acc[b]))));
        }
    }
#pragma unroll
    for (int b = 0; b < 8; ++b)
#pragma unroll
        for (int off = 32; off > 0; off >>= 1) acc[b] += __shfl_down(acc[b], off);
    __shared__ float red[4][8];
    const int wave = threadIdx.x >> 6;
    if ((threadIdx.x & 63) == 0)
#pragma unroll
        for (int b = 0; b < 8; ++b) red[wave][b] = acc[b];
    __syncthreads();
    if (threadIdx.x < 8) {
        partials[(j * 16 + kc) * 8 + threadIdx.x] =
            red[0][threadIdx.x] + red[1][threadIdx.x] + red[2][threadIdx.x] + red[3][threadIdx.x];
    }
}

// ---------------- K4: fc1-reduce + bias/relu + fc2 + tanh + rigid + moved/reg ----------
__global__ __launch_bounds__(1024) void k_fc2_moved(const float* __restrict__ partials,
                                                    const float* __restrict__ f1b,
                                                    const float* __restrict__ w,
                                                    const float* __restrict__ bias,
                                                    const float* __restrict__ pos,
                                                    const float* __restrict__ centers,
                                                    float* __restrict__ rt,
                                                    float* __restrict__ movedOut,
                                                    float* __restrict__ regOut) {
    __shared__ float sfo[256];
    __shared__ float srt[64 * 8];
    __shared__ float red[8][128];
    const int tid = threadIdx.x;
    if (tid < 256) {
        const int b = tid >> 5, j = tid & 31;
        float s = 0.f;
#pragma unroll
        for (int kc = 0; kc < 16; ++kc) s += partials[(j * 16 + kc) * 8 + b];
        sfo[b * 32 + j] = fmaxf(s + f1b[j], 0.f);
    }
    __syncthreads();
    if (tid < 64) {
        const int b = tid >> 3, t = tid & 7;
        const float* f = &sfo[b * 32];
        float th[6];
#pragma unroll
        for (int i = 0; i < 6; ++i) {
            const int o = t * 6 + i;
            float s = bias[o];
            const float* wr = w + o * 32;
#pragma unroll
            for (int k = 0; k < 32; ++k) s = fmaf(f[k], wr[k], s);
            th[i] = tanhf(s);
        }
        float s0, c0, s1, c1, s2, c2;
        sincosf(PI_F * th[0], &s0, &c0);
        sincosf(PI_F * th[1], &s1, &c1);
        sincosf(PI_F * th[2], &s2, &c2);
        const float R00 = c0 * c1, R10 = s0 * c1, R20 = -s1;
        const float R01 = -s0 * c2 + c0 * s1 * s2;
        const float R11 =  c0 * c2 + s0 * s1 * s2;
        const float R21 =  c1 * s2;
        const float T0 = th[3] * 128.f + 64.f - (64.f * R00 + 64.f * R10 + 4.f * R20);
        const float T1 = th[4] * 128.f + 64.f - (64.f * R01 + 64.f * R11 + 4.f * R21);
        float* o = srt + tid * 8;
        o[0] = R00; o[1] = R10; o[2] = R20; o[3] = T0;
        o[4] = R01; o[5] = R11; o[6] = R21; o[7] = T1;
        float* og = rt + tid * 8;
        og[0] = R00; og[1] = R10; og[2] = R20; og[3] = T0;
        og[4] = R01; og[5] = R11; og[6] = R21; og[7] = T1;
    }
    __syncthreads();
    const int b = tid >> 7, p = tid & 127;
    float nrm = 0.f;
    if (p < 100) {
        const float* pp = pos + ((size_t)b * 100 + p) * 3;
        const float p0 = pp[0], p1 = pp[1], p2 = pp[2];
        int i0 = (int)rintf(p0); i0 = i0 < 0 ? 0 : (i0 > 127 ? 127 : i0);
        int i1 = (int)rintf(p1); i1 = i1 < 0 ? 0 : (i1 > 127 ? 127 : i1);
        int i2 = (int)rintf(p2); i2 = i2 < 0 ? 0 : (i2 > 7 ? 7 : i2);
        const float gi = (float)i0, gj = (float)i1, gk = (float)i2;
        const float tsx[8] = {32.f, 32.f, 96.f, 96.f, 32.f, 96.f, 64.f, 64.f};
        const float tsy[8] = {32.f, 96.f, 32.f, 96.f, 64.f, 64.f, 32.f, 96.f};
        float u0 = 0.f, u1 = 0.f, es = 0.f;
#pragma unroll
        for (int t = 0; t < 8; ++t) {
            float dx = gi - tsx[t], dy = gj - tsy[t], dz = gk - 4.f;
            float d = sqrtf(dx * dx + dy * dy + dz * dz);
            float e = expf(-d / 10.f);
            const float* r = srt + (b * 8 + t) * 8;
            float f0 = fmaf(gi, r[0], fmaf(gj, r[1], fmaf(gk, r[2], r[3])));
            float f1 = fmaf(gi, r[4], fmaf(gj, r[5], fmaf(gk, r[6], r[7])));
            u0 = fmaf(e, f0, u0);
            u1 = fmaf(e, f1, u1);
            es += e;
        }
        const float inv = 1.f / es;
        const float nf0 = (u0 * inv) * (1.f / 64.f) - 1.f;
        const float nf1 = (u1 * inv) * (1.f / 64.f) - 1.f;
        const float m0 = 2.f * p0 - (0.5f + 0.5f * nf0) * 127.f;
        const float m1 = 2.f * p1 - (0.5f + 0.5f * nf1) * 127.f;
        const float m2 = 2.f * p2 - 3.5f;
        float* mo = movedOut + ((size_t)b * 100 + p) * 3;
        mo[0] = m0; mo[1] = m1; mo[2] = m2;
        const float* ce = centers + p * 3;
        const float d0 = m0 - ce[0], d1 = m1 - ce[1], d2 = m2 - ce[2];
        nrm = sqrtf(d0 * d0 + d1 * d1 + d2 * d2);
    }
    red[b][p] = nrm;
    __syncthreads();
    for (int s = 64; s > 0; s >>= 1) {
        if (p < s) red[b][p] += red[b][p + s];
        __syncthreads();
    }
    if (p == 0) regOut[b] = red[b][0] * 0.01f;
}

// ---------------- K5: flow field + grid output + trilinear grid-sample (fused) ----------
__global__ __launch_bounds__(256) void k_flow_sample(const float* __restrict__ x,
                                                     const float* __restrict__ rt,
                                                     float* __restrict__ outXt,
                                                     float* __restrict__ outGrid) {
    const int b = blockIdx.y;
    const int l = blockIdx.x * 256 + threadIdx.x;   // voxel index, 131072 per batch
    __shared__ float srt[64];
    __shared__ float sg[768];
    if (threadIdx.x < 64) srt[threadIdx.x] = rt[b * 64 + threadIdx.x];
    __syncthreads();

    const float gi = (float)(l >> 10);
    const float gj = (float)((l >> 3) & 127);
    const float gk = (float)(l & 7);

    const float tsx[8] = {32.f, 32.f, 96.f, 96.f, 32.f, 96.f, 64.f, 64.f};
    const float tsy[8] = {32.f, 96.f, 32.f, 96.f, 64.f, 64.f, 32.f, 96.f};

    float u0 = 0.f, u1 = 0.f, es = 0.f;
#pragma unroll
    for (int t = 0; t < 8; ++t) {
        float dx = gi - tsx[t], dy = gj - tsy[t], dz = gk - 4.f;
        float d = sqrtf(dx * dx + dy * dy + dz * dz);
        float e = expf(-d / 10.f);
        const float4 ra = *reinterpret_cast<const float4*>(&srt[t * 8]);
        const float4 rb = *reinterpret_cast<const float4*>(&srt[t * 8 + 4]);
        float f0 = fmaf(gi, ra.x, fmaf(gj, ra.y, fmaf(gk, ra.z, ra.w)));
        float f1 = fmaf(gi, rb.x, fmaf(gj, rb.y, fmaf(gk, rb.z, rb.w)));
        u0 = fmaf(e, f0, u0);
        u1 = fmaf(e, f1, u1);
        es += e;
    }
    const float inv = 1.f / es;
    const float fs0 = u0 * inv, fs1 = u1 * inv;
    const float nf0 = fs0 * (1.f / 64.f) - 1.f;
    const float nf1 = fs1 * (1.f / 64.f) - 1.f;

    // coalesced grid store via LDS transpose
    sg[threadIdx.x * 3 + 0] = 0.f;
    sg[threadIdx.x * 3 + 1] = nf1;
    sg[threadIdx.x * 3 + 2] = nf0;
    __syncthreads();
    if (threadIdx.x < 192) {
        *reinterpret_cast<float4*>(outGrid + (size_t)b * 393216 + (size_t)blockIdx.x * 768 +
                                   threadIdx.x * 4) = *reinterpret_cast<float4*>(&sg[threadIdx.x * 4]);
    }

    const float iz = fs0 - 0.5f, iy = fs1 - 0.5f;
    const float z0f = floorf(iz), y0f = floorf(iy);
    const float fz = iz - z0f, fy = iy - y0f;
    const int z0 = (int)z0f, y0 = (int)y0f;
    float s0 = 0.f, s1 = 0.f, s2 = 0.f, s3 = 0.f;
    const float* xb = x + (size_t)b * 4 * 131072;
#pragma unroll
    for (int dz = 0; dz < 2; ++dz) {
        const int zc = z0 + dz;
        if (zc < 0 || zc > 127) continue;
        const float wz = dz ? fz : 1.f - fz;
#pragma unroll
        for (int dy = 0; dy < 2; ++dy) {
            const int yc = y0 + dy;
            if (yc < 0 || yc > 127) continue;
            const float wv = wz * (dy ? fy : 1.f - fy) * 0.5f;
            const float* p = xb + ((size_t)zc * 128 + yc) * 8 + 3;
            s0 = fmaf(wv, p[0] + p[1], s0);
            s1 = fmaf(wv, p[131072] + p[131073], s1);
            s2 = fmaf(wv, p[262144] + p[262145], s2);
            s3 = fmaf(wv, p[393216] + p[393217], s3);
        }
    }
    float* o = outXt + (size_t)b * 4 * 131072 + l;
    o[0] = s0; o[131072] = s1; o[262144] = s2; o[393216] = s3;
}

// ---------------- launch ----------------
extern "C" void kernel_launch(void* const* d_in, const int* in_sizes, int n_in,
                              void* d_out, int out_size, void* d_ws, size_t ws_size,
                              hipStream_t stream) {
    const float* x       = (const float*)d_in[0];
    const float* pos     = (const float*)d_in[1];
    const float* centers = (const float*)d_in[2];
    const float* c1w     = (const float*)d_in[3];
    const float* c1b     = (const float*)d_in[4];
    const float* c2w     = (const float*)d_in[5];
    const float* c2b     = (const float*)d_in[6];
    const float* f1w     = (const float*)d_in[7];
    const float* f1b     = (const float*)d_in[8];
    const float* f2w     = (const float*)d_in[9];
    const float* f2b     = (const float*)d_in[10];

    float* out = (float*)d_out;
    float* ws  = (float*)d_ws;

    // workspace layout (floats)
    float* h1       = ws;                      // 8*8*61*61*8   = 1,905,152
    float* h2       = h1 + 1905152;            // 8*10*28*28*8  =   501,760
    float* partials = h2 + 501760;             // 32*16*8       =     4,096
    float* rt       = partials + 4096;         // 8*8*8         =       512

    // output layout (floats): X_t | grid | reg | moved
    float* outXt    = out;                         // 4,194,304
    float* outGrid  = out + 4194304;               // 3,145,728
    float* outReg   = out + 4194304 + 3145728;     // 8
    float* outMoved = outReg + 8;                  // 2,400

    // weight stash in tail of outGrid — fully overwritten by k_flow_sample afterwards
    uint32* wt1m = (uint32*)(out + 4194304 + 3145728 - 4096);   // 1792 dwords
    uint32* wt2h = wt1m + 1792;                                  // 1000 dwords

    k_prep<<<1, 256, 0, stream>>>(c1w, c2w, wt1m, wt2h);
    k_conv1<<<dim3(256, 8), 256, 0, stream>>>(x, wt1m, c1b, h1);
    k_conv2<<<dim3(98, 8), 256, 0, stream>>>(h1, wt2h, c2b, h2);
    k_fc1<<<512, 256, 0, stream>>>(h2, f1w, partials);
    k_fc2_moved<<<1, 1024, 0, stream>>>(partials, f1b, f2w, f2b, pos, centers, rt, outMoved, outReg);
    k_flow_sample<<<dim3(512, 8), 256, 0, stream>>>(x, rt, outXt, outGrid);
}

// Round 14
// 85.309 us; speedup vs baseline: 1.4005x; 1.0290x over previous
//
#include <hip/hip_runtime.h>

#define PI_F 3.14159265358979323846f

typedef _Float16 h2t __attribute__((ext_vector_type(2)));
typedef __fp16 fp16x2 __attribute__((ext_vector_type(2)));
typedef _Float16 f16x8 __attribute__((ext_vector_type(8)));
typedef float f32x4 __attribute__((ext_vector_type(4)));
typedef unsigned int uint32;

__device__ __forceinline__ uint32 packh(float a, float b) {   // RNE, for prep
    h2t h = {(_Float16)a, (_Float16)b};
    return __builtin_bit_cast(uint32, h);
}
__device__ __forceinline__ uint32 pkrtz(float a, float b) {   // fast, for staging
    fp16x2 h = __builtin_amdgcn_cvt_pkrtz(a, b);
    return __builtin_bit_cast(uint32, h);
}

// ---------------- K0: pack MFMA B-fragments for conv1 + conv2 ----------------
// wt1m[((ks*4+c)*16+oc)*4 + h*2 + icp]: tap = 8ks+c+4h (7x7 conv, 4 ic as 2 pairs)
// wt2m[((ks*4+c)*16+oc)*4 + d]:         tap = 4ks+c    (5x5 conv, 8 ic as 4 pairs)
__global__ void k_prep(const float* __restrict__ w1, const float* __restrict__ w2,
                       uint32* __restrict__ wt1m, uint32* __restrict__ wt2m) {
    const int tid = threadIdx.x;
    for (int i = tid; i < 1792; i += 256) {
        const int idx4 = i >> 2, rem = i & 3;
        const int h = rem >> 1, icp = rem & 1;
        const int oc = idx4 & 15, kc = idx4 >> 4;
        const int ks = kc >> 2, c = kc & 3;
        const int tap = 8 * ks + c + 4 * h;
        uint32 v = 0;
        if (tap < 49 && oc < 8)
            v = packh(w1[(oc * 4 + 2 * icp) * 49 + tap],
                      w1[(oc * 4 + 2 * icp + 1) * 49 + tap]);
        wt1m[i] = v;
    }
    for (int i = tid; i < 1792; i += 256) {
        const int idx4 = i >> 2, d = i & 3;
        const int oc = idx4 & 15, kc = idx4 >> 4;
        const int ks = kc >> 2, c = kc & 3;
        const int tap = 4 * ks + c;
        uint32 v = 0;
        if (tap < 25 && oc < 10)
            v = packh(w2[(oc * 8 + 2 * d) * 25 + tap],
                      w2[(oc * 8 + 2 * d + 1) * 25 + tap]);
        wt2m[i] = v;
    }
}

// ---------------- K1: conv1 via MFMA 16x16x32_f16 (unchanged from R13) ----------------
__global__ __launch_bounds__(256) void k_conv1(const float* __restrict__ x,
                                               const uint32* __restrict__ wt1m,
                                               const float* __restrict__ b1,
                                               float* __restrict__ h1) {
    const int b = blockIdx.y;
    const int ty = blockIdx.x >> 4, tx = blockIdx.x & 15;   // 16 x 16 tiles
    const int py0 = ty * 4, px0 = tx * 4;
    const int iy0 = py0 * 2, ix0 = px0 * 2;

    __shared__ uint32 tin[14 * 15 * 16];   // dword idx = (r*15+c)*16 + w*2 + icp

    const int tid = threadIdx.x;

    const float* xb = x + (size_t)b * 4 * 131072;
    for (int s = tid; s < 392; s += 256) {
        const int r = s / 28, rem = s % 28, c = rem >> 1, wqs = rem & 1;
        const int row = min(iy0 + r, 127), col = min(ix0 + c, 127);
        const float* base = xb + ((size_t)row * 128 + col) * 8 + wqs * 4;
        const float4 f0 = *reinterpret_cast<const float4*>(base);
        const float4 f1 = *reinterpret_cast<const float4*>(base + 131072);
        const float4 f2 = *reinterpret_cast<const float4*>(base + 262144);
        const float4 f3 = *reinterpret_cast<const float4*>(base + 393216);
        const int bi = (r * 15 + c) * 16 + wqs * 8;
        *reinterpret_cast<uint2*>(&tin[bi + 0]) = make_uint2(pkrtz(f0.x, f1.x), pkrtz(f2.x, f3.x));
        *reinterpret_cast<uint2*>(&tin[bi + 2]) = make_uint2(pkrtz(f0.y, f1.y), pkrtz(f2.y, f3.y));
        *reinterpret_cast<uint2*>(&tin[bi + 4]) = make_uint2(pkrtz(f0.z, f1.z), pkrtz(f2.z, f3.z));
        *reinterpret_cast<uint2*>(&tin[bi + 6]) = make_uint2(pkrtz(f0.w, f1.w), pkrtz(f2.w, f3.w));
    }

    const int lane = tid & 63;
    const int wv   = tid >> 6;
    const int kc   = lane >> 4;
    const int arow = lane & 15;
    const int q    = arow >> 2, cp = arow & 3;
    const int cpy  = cp >> 1,  cpx = cp & 1;

    f16x8 Bf[7];
#pragma unroll
    for (int ks = 0; ks < 7; ++ks) {
        const uint4 t = *reinterpret_cast<const uint4*>(wt1m + (ks * 64 + lane) * 4);
        Bf[ks] = __builtin_bit_cast(f16x8, t);
    }

    int offs[7][2];
#pragma unroll
    for (int ks = 0; ks < 7; ++ks) {
#pragma unroll
        for (int h = 0; h < 2; ++h) {
            int tap = 8 * ks + kc + 4 * h;
            if (tap > 48) tap = 48;
            const int kd = tap / 7, kh = tap % 7;
            offs[ks][h] = ((2 * wv + cpy + kd) * 15 + (2 * q + cpx + kh)) * 16;
        }
    }

    __syncthreads();

    f32x4 acc[8];
#pragma unroll
    for (int w = 0; w < 8; ++w) acc[w] = (f32x4)(0.f);

#pragma unroll
    for (int w = 0; w < 8; ++w) {
#pragma unroll
        for (int ks = 0; ks < 7; ++ks) {
            const uint2 lo = *reinterpret_cast<const uint2*>(&tin[offs[ks][0] + w * 2]);
            const uint2 hi = *reinterpret_cast<const uint2*>(&tin[offs[ks][1] + w * 2]);
            const uint4 a4 = make_uint4(lo.x, lo.y, hi.x, hi.y);
            acc[w] = __builtin_amdgcn_mfma_f32_16x16x32_f16(
                __builtin_bit_cast(f16x8, a4), Bf[ks], acc[w], 0, 0, 0);
        }
    }

    const int oc = lane & 15, qo = lane >> 4;
    const int pi = py0 + wv, pjg = px0 + qo;
    if (oc < 8 && pi < 61 && pjg < 61) {
        const float bb = b1[oc];
        float vals[8];
#pragma unroll
        for (int w = 0; w < 8; ++w) {
            const float m = fmaxf(fmaxf(acc[w][0], acc[w][1]), fmaxf(acc[w][2], acc[w][3]));
            vals[w] = fmaxf(m + bb, 0.f);
        }
        float* base = h1 + ((((size_t)b * 8 + oc) * 61 + pi) * 61 + pjg) * 8;
        *reinterpret_cast<float4*>(base)     = make_float4(vals[0], vals[1], vals[2], vals[3]);
        *reinterpret_cast<float4*>(base + 4) = make_float4(vals[4], vals[5], vals[6], vals[7]);
    }
}

// ---------------- K2: conv2 via MFMA 16x16x32_f16 ----------------
// h1:(8,8,61,61,8) -> h2:(8,10,28,28,8).
// N=oc(10/16), K=(tap25,ic8) 7 steps x 32 (tap=4ks+kc, 8 ic per lane = 1 ds_read_b128),
// M = 4 pooled-col x 4 conv-quad; wave = pooled row; tile 4x4 pooled; grid 49 x 8.
__global__ __launch_bounds__(256) void k_conv2(const float* __restrict__ h1,
                                               const uint32* __restrict__ wt2m,
                                               const float* __restrict__ b2,
                                               float* __restrict__ h2) {
    const int b = blockIdx.y;
    const int ty = blockIdx.x / 7, tx = blockIdx.x % 7;    // 7 x 7 tiles of 4x4 pooled
    const int py0 = ty * 4, px0 = tx * 4;
    const int iy0 = py0 * 2, ix0 = px0 * 2;

    __shared__ uint32 tin[12 * 12 * 32];   // dword idx = (r*12+c)*32 + w*4 + d

    const int tid = threadIdx.x;

    // staging: 144 pos x 2 w-quads; pack 8 ic to 4 dword-pairs per w
    const float* hb = h1 + (size_t)b * 8 * 29768;
    for (int s = tid; s < 288; s += 256) {
        const int pos = s >> 1, wqs = s & 1;
        const int r = pos / 12, c = pos % 12;
        const float* base = hb + ((size_t)(iy0 + r) * 61 + ix0 + c) * 8 + wqs * 4;
        const float4 f0 = *reinterpret_cast<const float4*>(base);
        const float4 f1 = *reinterpret_cast<const float4*>(base + 29768);
        const float4 f2 = *reinterpret_cast<const float4*>(base + 2 * 29768);
        const float4 f3 = *reinterpret_cast<const float4*>(base + 3 * 29768);
        const float4 f4 = *reinterpret_cast<const float4*>(base + 4 * 29768);
        const float4 f5 = *reinterpret_cast<const float4*>(base + 5 * 29768);
        const float4 f6 = *reinterpret_cast<const float4*>(base + 6 * 29768);
        const float4 f7 = *reinterpret_cast<const float4*>(base + 7 * 29768);
        const int bi = (r * 12 + c) * 32 + wqs * 16;
        *reinterpret_cast<uint4*>(&tin[bi +  0]) = make_uint4(pkrtz(f0.x, f1.x), pkrtz(f2.x, f3.x), pkrtz(f4.x, f5.x), pkrtz(f6.x, f7.x));
        *reinterpret_cast<uint4*>(&tin[bi +  4]) = make_uint4(pkrtz(f0.y, f1.y), pkrtz(f2.y, f3.y), pkrtz(f4.y, f5.y), pkrtz(f6.y, f7.y));
        *reinterpret_cast<uint4*>(&tin[bi +  8]) = make_uint4(pkrtz(f0.z, f1.z), pkrtz(f2.z, f3.z), pkrtz(f4.z, f5.z), pkrtz(f6.z, f7.z));
        *reinterpret_cast<uint4*>(&tin[bi + 12]) = make_uint4(pkrtz(f0.w, f1.w), pkrtz(f2.w, f3.w), pkrtz(f4.w, f5.w), pkrtz(f6.w, f7.w));
    }

    const int lane = tid & 63;
    const int wv   = tid >> 6;         // pooled row
    const int kc   = lane >> 4;
    const int arow = lane & 15;
    const int q    = arow >> 2, cp = arow & 3;
    const int cpy  = cp >> 1,  cpx = cp & 1;

    f16x8 Bf[7];
#pragma unroll
    for (int ks = 0; ks < 7; ++ks) {
        const uint4 t = *reinterpret_cast<const uint4*>(wt2m + (ks * 64 + lane) * 4);
        Bf[ks] = __builtin_bit_cast(f16x8, t);
    }

    int offs[7];
#pragma unroll
    for (int ks = 0; ks < 7; ++ks) {
        int tap = 4 * ks + kc;
        if (tap > 24) tap = 24;        // B is zero there
        const int kd = tap / 5, kh = tap % 5;
        offs[ks] = ((2 * wv + cpy + kd) * 12 + (2 * q + cpx + kh)) * 32;
    }

    __syncthreads();

    f32x4 acc[8];
#pragma unroll
    for (int w = 0; w < 8; ++w) acc[w] = (f32x4)(0.f);

#pragma unroll
    for (int w = 0; w < 8; ++w) {
#pragma unroll
        for (int ks = 0; ks < 7; ++ks) {
            const uint4 a4 = *reinterpret_cast<const uint4*>(&tin[offs[ks] + w * 4]);
            acc[w] = __builtin_amdgcn_mfma_f32_16x16x32_f16(
                __builtin_bit_cast(f16x8, a4), Bf[ks], acc[w], 0, 0, 0);
        }
    }

    const int oc = lane & 15, qo = lane >> 4;
    const int pi = py0 + wv, pjg = px0 + qo;   // < 28 always
    if (oc < 10) {
        const float bb = b2[oc];
        float vals[8];
#pragma unroll
        for (int w = 0; w < 8; ++w) {
            const float m = fmaxf(fmaxf(acc[w][0], acc[w][1]), fmaxf(acc[w][2], acc[w][3]));
            vals[w] = fmaxf(m + bb, 0.f);
        }
        float* base = h2 + ((((size_t)b * 10 + oc) * 28 + pi) * 28 + pjg) * 8;
        *reinterpret_cast<float4*>(base)     = make_float4(vals[0], vals[1], vals[2], vals[3]);
        *reinterpret_cast<float4*>(base + 4) = make_float4(vals[4], vals[5], vals[6], vals[7]);
    }
}

// ---------------- K3: fc1 (62720 -> 32), split-K, partials to ws ----------------
__global__ __launch_bounds__(256) void k_fc1(const float* __restrict__ feat,
                                             const float* __restrict__ w,
                                             float* __restrict__ partials) {
    const int j = blockIdx.x >> 4;
    const int kc = blockIdx.x & 15;
    const int k0 = kc * 3920;
    const float4* w4 = reinterpret_cast<const float4*>(w + (size_t)j * 62720 + k0);
    float acc[8];
#pragma unroll
    for (int b = 0; b < 8; ++b) acc[b] = 0.f;
    for (int i = threadIdx.x; i < 980; i += 256) {
        const float4 wv = w4[i];
#pragma unroll
        for (int b = 0; b < 8; ++b) {
            const float4 fv = *reinterpret_cast<const float4*>(feat + (size_t)b * 62720 + k0 + i * 4);
            acc[b] = fmaf(wv.x, fv.x, fmaf(wv.y, fv.y, fmaf(wv.z, fv.z, fmaf(wv.w, fv.w, acc[b]))));
        }
    }
#pragma unroll
    for (int b = 0; b < 8; ++b)
#pragma unroll
        for (int off = 32; off > 0; off >>= 1) acc[b] += __shfl_down(acc[b], off);
    __shared__ float red[4][8];
    const int wave = threadIdx.x >> 6;
    if ((threadIdx.x & 63) == 0)
#pragma unroll
        for (int b = 0; b < 8; ++b) red[wave][b] = acc[b];
    __syncthreads();
    if (threadIdx.x < 8) {
        partials[(j * 16 + kc) * 8 + threadIdx.x] =
            red[0][threadIdx.x] + red[1][threadIdx.x] + red[2][threadIdx.x] + red[3][threadIdx.x];
    }
}

// ---------------- K4: fc1-reduce + fc2 + rigid (in-block) + flow + sample + moved ------
__global__ __launch_bounds__(256) void k_flow_all(const float* __restrict__ x,
                                                  const float* __restrict__ partials,
                                                  const float* __restrict__ f1b,
                                                  const float* __restrict__ f2w,
                                                  const float* __restrict__ f2b,
                                                  const float* __restrict__ pos,
                                                  const float* __restrict__ centers,
                                                  float* __restrict__ outXt,
                                                  float* __restrict__ outGrid,
                                                  float* __restrict__ movedOut,
                                                  float* __restrict__ regOut) {
    const int b = blockIdx.y;
    const int tid = threadIdx.x;
    const int l = blockIdx.x * 256 + tid;

    __shared__ float sfo[32];
    __shared__ float srt[64];
    __shared__ float sg[768];
    __shared__ float red[128];

    if (tid < 32) {
        float s = 0.f;
#pragma unroll
        for (int kc = 0; kc < 16; ++kc) s += partials[(tid * 16 + kc) * 8 + b];
        sfo[tid] = fmaxf(s + f1b[tid], 0.f);
    }
    __syncthreads();
    if (tid < 8) {
        const int t = tid;
        float th[6];
#pragma unroll
        for (int i = 0; i < 6; ++i) {
            const int o = t * 6 + i;
            float s = f2b[o];
            const float* wr = f2w + o * 32;
#pragma unroll
            for (int k = 0; k < 32; ++k) s = fmaf(sfo[k], wr[k], s);
            th[i] = tanhf(s);
        }
        float s0, c0, s1, c1, s2, c2;
        sincosf(PI_F * th[0], &s0, &c0);
        sincosf(PI_F * th[1], &s1, &c1);
        sincosf(PI_F * th[2], &s2, &c2);
        const float R00 = c0 * c1, R10 = s0 * c1, R20 = -s1;
        const float R01 = -s0 * c2 + c0 * s1 * s2;
        const float R11 =  c0 * c2 + s0 * s1 * s2;
        const float R21 =  c1 * s2;
        const float T0 = th[3] * 128.f + 64.f - (64.f * R00 + 64.f * R10 + 4.f * R20);
        const float T1 = th[4] * 128.f + 64.f - (64.f * R01 + 64.f * R11 + 4.f * R21);
        float* o = srt + t * 8;
        o[0] = R00; o[1] = R10; o[2] = R20; o[3] = T0;
        o[4] = R01; o[5] = R11; o[6] = R21; o[7] = T1;
    }
    __syncthreads();

    const float gi = (float)(l >> 10);
    const float gj = (float)((l >> 3) & 127);
    const float gk = (float)(l & 7);

    const float tsx[8] = {32.f, 32.f, 96.f, 96.f, 32.f, 96.f, 64.f, 64.f};
    const float tsy[8] = {32.f, 96.f, 32.f, 96.f, 64.f, 64.f, 32.f, 96.f};

    float u0 = 0.f, u1 = 0.f, es = 0.f;
#pragma unroll
    for (int t = 0; t < 8; ++t) {
        float dx = gi - tsx[t], dy = gj - tsy[t], dz = gk - 4.f;
        float d = sqrtf(dx * dx + dy * dy + dz * dz);
        float e = expf(-d / 10.f);
        const float4 ra = *reinterpret_cast<const float4*>(&srt[t * 8]);
        const float4 rb = *reinterpret_cast<const float4*>(&srt[t * 8 + 4]);
        float f0 = fmaf(gi, ra.x, fmaf(gj, ra.y, fmaf(gk, ra.z, ra.w)));
        float f1 = fmaf(gi, rb.x, fmaf(gj, rb.y, fmaf(gk, rb.z, rb.w)));
        u0 = fmaf(e, f0, u0);
        u1 = fmaf(e, f1, u1);
        es += e;
    }
    const float inv = 1.f / es;
    const float fs0 = u0 * inv, fs1 = u1 * inv;
    const float nf0 = fs0 * (1.f / 64.f) - 1.f;
    const float nf1 = fs1 * (1.f / 64.f) - 1.f;

    // coalesced grid store via LDS transpose
    sg[tid * 3 + 0] = 0.f;
    sg[tid * 3 + 1] = nf1;
    sg[tid * 3 + 2] = nf0;
    __syncthreads();
    if (tid < 192) {
        *reinterpret_cast<float4*>(outGrid + (size_t)b * 393216 + (size_t)blockIdx.x * 768 +
                                   tid * 4) = *reinterpret_cast<float4*>(&sg[tid * 4]);
    }

    const float iz = fs0 - 0.5f, iy = fs1 - 0.5f;
    const float z0f = floorf(iz), y0f = floorf(iy);
    const float fz = iz - z0f, fy = iy - y0f;
    const int z0 = (int)z0f, y0 = (int)y0f;
    float s0 = 0.f, s1 = 0.f, s2 = 0.f, s3 = 0.f;
    const float* xb = x + (size_t)b * 4 * 131072;
#pragma unroll
    for (int dz = 0; dz < 2; ++dz) {
        const int zc = z0 + dz;
        if (zc < 0 || zc > 127) continue;
        const float wz = dz ? fz : 1.f - fz;
#pragma unroll
        for (int dy = 0; dy < 2; ++dy) {
            const int yc = y0 + dy;
            if (yc < 0 || yc > 127) continue;
            const float wv = wz * (dy ? fy : 1.f - fy) * 0.5f;
            const float* p = xb + ((size_t)zc * 128 + yc) * 8 + 3;
            s0 = fmaf(wv, p[0] + p[1], s0);
            s1 = fmaf(wv, p[131072] + p[131073], s1);
            s2 = fmaf(wv, p[262144] + p[262145], s2);
            s3 = fmaf(wv, p[393216] + p[393217], s3);
        }
    }
    float* o = outXt + (size_t)b * 4 * 131072 + l;
    o[0] = s0; o[131072] = s1; o[262144] = s2; o[393216] = s3;

    // block x==0: moved + reg for batch b (uses srt analytically)
    if (blockIdx.x == 0) {
        float nrm = 0.f;
        if (tid < 128) {
            const int p = tid;
            if (p < 100) {
                const float* pp = pos + ((size_t)b * 100 + p) * 3;
                const float p0 = pp[0], p1 = pp[1], p2 = pp[2];
                int i0 = (int)rintf(p0); i0 = i0 < 0 ? 0 : (i0 > 127 ? 127 : i0);
                int i1 = (int)rintf(p1); i1 = i1 < 0 ? 0 : (i1 > 127 ? 127 : i1);
                int i2 = (int)rintf(p2); i2 = i2 < 0 ? 0 : (i2 > 7 ? 7 : i2);
                const float qi = (float)i0, qj = (float)i1, qk = (float)i2;
                float v0 = 0.f, v1 = 0.f, esm = 0.f;
#pragma unroll
                for (int t = 0; t < 8; ++t) {
                    float dx = qi - tsx[t], dy = qj - tsy[t], dz = qk - 4.f;
                    float d = sqrtf(dx * dx + dy * dy + dz * dz);
                    float e = expf(-d / 10.f);
                    const float* r = srt + t * 8;
                    float f0 = fmaf(qi, r[0], fmaf(qj, r[1], fmaf(qk, r[2], r[3])));
                    float f1 = fmaf(qi, r[4], fmaf(qj, r[5], fmaf(qk, r[6], r[7])));
                    v0 = fmaf(e, f0, v0);
                    v1 = fmaf(e, f1, v1);
                    esm += e;
                }
                const float invm = 1.f / esm;
                const float m0 = 2.f * p0 - (0.5f + 0.5f * ((v0 * invm) * (1.f / 64.f) - 1.f)) * 127.f;
                const float m1 = 2.f * p1 - (0.5f + 0.5f * ((v1 * invm) * (1.f / 64.f) - 1.f)) * 127.f;
                const float m2 = 2.f * p2 - 3.5f;
                float* mo = movedOut + ((size_t)b * 100 + p) * 3;
                mo[0] = m0; mo[1] = m1; mo[2] = m2;
                const float* ce = centers + p * 3;
                const float d0 = m0 - ce[0], d1 = m1 - ce[1], d2 = m2 - ce[2];
                nrm = sqrtf(d0 * d0 + d1 * d1 + d2 * d2);
            }
            red[tid] = nrm;
        }
        __syncthreads();
        for (int s = 64; s > 0; s >>= 1) {
            if (tid < s) red[tid] += red[tid + s];
            __syncthreads();
        }
        if (tid == 0) regOut[b] = red[0] * 0.01f;
    }
}

// ---------------- launch ----------------
extern "C" void kernel_launch(void* const* d_in, const int* in_sizes, int n_in,
                              void* d_out, int out_size, void* d_ws, size_t ws_size,
                              hipStream_t stream) {
    const float* x       = (const float*)d_in[0];
    const float* pos     = (const float*)d_in[1];
    const float* centers = (const float*)d_in[2];
    const float* c1w     = (const float*)d_in[3];
    const float* c1b     = (const float*)d_in[4];
    const float* c2w     = (const float*)d_in[5];
    const float* c2b     = (const float*)d_in[6];
    const float* f1w     = (const float*)d_in[7];
    const float* f1b     = (const float*)d_in[8];
    const float* f2w     = (const float*)d_in[9];
    const float* f2b     = (const float*)d_in[10];

    float* out = (float*)d_out;
    float* ws  = (float*)d_ws;

    // workspace layout (floats)
    float* h1       = ws;                      // 8*8*61*61*8   = 1,905,152
    float* h2       = h1 + 1905152;            // 8*10*28*28*8  =   501,760
    float* partials = h2 + 501760;             // 32*16*8       =     4,096

    // output layout (floats): X_t | grid | reg | moved
    float* outXt    = out;                         // 4,194,304
    float* outGrid  = out + 4194304;               // 3,145,728
    float* outReg   = out + 4194304 + 3145728;     // 8
    float* outMoved = outReg + 8;                  // 2,400

    // weight stash in tail of outGrid — fully overwritten by k_flow_all afterwards
    uint32* wt1m = (uint32*)(out + 4194304 + 3145728 - 4096);   // 1792 dwords
    uint32* wt2m = wt1m + 1792;                                  // 1792 dwords

    k_prep<<<1, 256, 0, stream>>>(c1w, c2w, wt1m, wt2m);
    k_conv1<<<dim3(256, 8), 256, 0, stream>>>(x, wt1m, c1b, h1);
    k_conv2<<<dim3(49, 8), 256, 0, stream>>>(h1, wt2m, c2b, h2);
    k_fc1<<<512, 256, 0, stream>>>(h2, f1w, partials);
    k_flow_all<<<dim3(512, 8), 256, 0, stream>>>(x, partials, f1b, f2w, f2b, pos, centers,
                                                 outXt, outGrid, outMoved, outReg);
}

// Round 15
// 67.848 us; speedup vs baseline: 1.7610x; 1.2574x over previous
//
#include <hip/hip_runtime.h>

#define PI_F 3.14159265358979323846f

typedef _Float16 h2t __attribute__((ext_vector_type(2)));
typedef __fp16 fp16x2 __attribute__((ext_vector_type(2)));
typedef _Float16 f16x8 __attribute__((ext_vector_type(8)));
typedef float f32x4 __attribute__((ext_vector_type(4)));
typedef unsigned int uint32;

__device__ __forceinline__ uint32 packh(float a, float b) {   // RNE, for prep
    h2t h = {(_Float16)a, (_Float16)b};
    return __builtin_bit_cast(uint32, h);
}
__device__ __forceinline__ uint32 pkrtz(float a, float b) {   // fast, for staging
    fp16x2 h = __builtin_amdgcn_cvt_pkrtz(a, b);
    return __builtin_bit_cast(uint32, h);
}

// ---------------- K0: pack MFMA B-fragments for conv1 + conv2 ----------------
// wt1m[((ks*4+c)*16+oc)*4 + h*2 + icp]: tap = 8ks+c+4h (7x7 conv, 4 ic as 2 pairs)
// wt2m[((ks*4+c)*16+oc)*4 + d]:         tap = 4ks+c    (5x5 conv, 8 ic as 4 pairs)
__global__ void k_prep(const float* __restrict__ w1, const float* __restrict__ w2,
                       uint32* __restrict__ wt1m, uint32* __restrict__ wt2m) {
    const int tid = threadIdx.x;
    for (int i = tid; i < 1792; i += 256) {
        const int idx4 = i >> 2, rem = i & 3;
        const int h = rem >> 1, icp = rem & 1;
        const int oc = idx4 & 15, kc = idx4 >> 4;
        const int ks = kc >> 2, c = kc & 3;
        const int tap = 8 * ks + c + 4 * h;
        uint32 v = 0;
        if (tap < 49 && oc < 8)
            v = packh(w1[(oc * 4 + 2 * icp) * 49 + tap],
                      w1[(oc * 4 + 2 * icp + 1) * 49 + tap]);
        wt1m[i] = v;
    }
    for (int i = tid; i < 1792; i += 256) {
        const int idx4 = i >> 2, d = i & 3;
        const int oc = idx4 & 15, kc = idx4 >> 4;
        const int ks = kc >> 2, c = kc & 3;
        const int tap = 4 * ks + c;
        uint32 v = 0;
        if (tap < 25 && oc < 10)
            v = packh(w2[(oc * 8 + 2 * d) * 25 + tap],
                      w2[(oc * 8 + 2 * d + 1) * 25 + tap]);
        wt2m[i] = v;
    }
}

// ---------------- K1: conv1 via MFMA 16x16x32_f16, XOR-swizzled LDS ----------------
// x:(8,4,128,128,8) -> h1:(8,8,61,61,8).
// tin dword idx = pos*16 + (w ^ (pos&7))*2 + icp   (pos = r*15+c).
// Swizzle spreads the per-w gather over all 32 banks (was 16-way conflict).
__global__ __launch_bounds__(256) void k_conv1(const float* __restrict__ x,
                                               const uint32* __restrict__ wt1m,
                                               const float* __restrict__ b1,
                                               float* __restrict__ h1) {
    const int b = blockIdx.y;
    const int ty = blockIdx.x >> 4, tx = blockIdx.x & 15;   // 16 x 16 tiles
    const int py0 = ty * 4, px0 = tx * 4;
    const int iy0 = py0 * 2, ix0 = px0 * 2;

    __shared__ uint32 tin[14 * 15 * 16];

    const int tid = threadIdx.x;

    const float* xb = x + (size_t)b * 4 * 131072;
    for (int s = tid; s < 392; s += 256) {
        const int r = s / 28, rem = s % 28, c = rem >> 1, wqs = rem & 1;
        const int row = min(iy0 + r, 127), col = min(ix0 + c, 127);
        const float* base = xb + ((size_t)row * 128 + col) * 8 + wqs * 4;
        const float4 f0 = *reinterpret_cast<const float4*>(base);
        const float4 f1 = *reinterpret_cast<const float4*>(base + 131072);
        const float4 f2 = *reinterpret_cast<const float4*>(base + 262144);
        const float4 f3 = *reinterpret_cast<const float4*>(base + 393216);
        const int pos = r * 15 + c;
        const int sw = pos & 7;
        const int bi = pos * 16;
        *reinterpret_cast<uint2*>(&tin[bi + (((wqs * 4 + 0) ^ sw) << 1)]) =
            make_uint2(pkrtz(f0.x, f1.x), pkrtz(f2.x, f3.x));
        *reinterpret_cast<uint2*>(&tin[bi + (((wqs * 4 + 1) ^ sw) << 1)]) =
            make_uint2(pkrtz(f0.y, f1.y), pkrtz(f2.y, f3.y));
        *reinterpret_cast<uint2*>(&tin[bi + (((wqs * 4 + 2) ^ sw) << 1)]) =
            make_uint2(pkrtz(f0.z, f1.z), pkrtz(f2.z, f3.z));
        *reinterpret_cast<uint2*>(&tin[bi + (((wqs * 4 + 3) ^ sw) << 1)]) =
            make_uint2(pkrtz(f0.w, f1.w), pkrtz(f2.w, f3.w));
    }

    const int lane = tid & 63;
    const int wv   = tid >> 6;
    const int kc   = lane >> 4;
    const int arow = lane & 15;
    const int q    = arow >> 2, cp = arow & 3;
    const int cpy  = cp >> 1,  cpx = cp & 1;

    f16x8 Bf[7];
#pragma unroll
    for (int ks = 0; ks < 7; ++ks) {
        const uint4 t = *reinterpret_cast<const uint4*>(wt1m + (ks * 64 + lane) * 4);
        Bf[ks] = __builtin_bit_cast(f16x8, t);
    }

    int offp[7][2], sw1[7][2];
#pragma unroll
    for (int ks = 0; ks < 7; ++ks) {
#pragma unroll
        for (int h = 0; h < 2; ++h) {
            int tap = 8 * ks + kc + 4 * h;
            if (tap > 48) tap = 48;
            const int kd = tap / 7, kh = tap % 7;
            const int pos = (2 * wv + cpy + kd) * 15 + (2 * q + cpx + kh);
            offp[ks][h] = pos * 16;
            sw1[ks][h]  = pos & 7;
        }
    }

    __syncthreads();

    f32x4 acc[8];
#pragma unroll
    for (int w = 0; w < 8; ++w) acc[w] = (f32x4)(0.f);

#pragma unroll
    for (int w = 0; w < 8; ++w) {
#pragma unroll
        for (int ks = 0; ks < 7; ++ks) {
            const uint2 lo = *reinterpret_cast<const uint2*>(
                &tin[offp[ks][0] + (((w ^ sw1[ks][0])) << 1)]);
            const uint2 hi = *reinterpret_cast<const uint2*>(
                &tin[offp[ks][1] + (((w ^ sw1[ks][1])) << 1)]);
            const uint4 a4 = make_uint4(lo.x, lo.y, hi.x, hi.y);
            acc[w] = __builtin_amdgcn_mfma_f32_16x16x32_f16(
                __builtin_bit_cast(f16x8, a4), Bf[ks], acc[w], 0, 0, 0);
        }
    }

    const int oc = lane & 15, qo = lane >> 4;
    const int pi = py0 + wv, pjg = px0 + qo;
    if (oc < 8 && pi < 61 && pjg < 61) {
        const float bb = b1[oc];
        float vals[8];
#pragma unroll
        for (int w = 0; w < 8; ++w) {
            const float m = fmaxf(fmaxf(acc[w][0], acc[w][1]), fmaxf(acc[w][2], acc[w][3]));
            vals[w] = fmaxf(m + bb, 0.f);
        }
        float* base = h1 + ((((size_t)b * 8 + oc) * 61 + pi) * 61 + pjg) * 8;
        *reinterpret_cast<float4*>(base)     = make_float4(vals[0], vals[1], vals[2], vals[3]);
        *reinterpret_cast<float4*>(base + 4) = make_float4(vals[4], vals[5], vals[6], vals[7]);
    }
}

// ---------------- K2: conv2 via MFMA 16x16x32_f16, XOR-swizzled LDS ----------------
// tin dword idx = pos*32 + (w ^ (pos&7))*4 + d   (pos = r*12+c).
__global__ __launch_bounds__(256) void k_conv2(const float* __restrict__ h1,
                                               const uint32* __restrict__ wt2m,
                                               const float* __restrict__ b2,
                                               float* __restrict__ h2) {
    const int b = blockIdx.y;
    const int ty = blockIdx.x / 7, tx = blockIdx.x % 7;    // 7 x 7 tiles of 4x4 pooled
    const int py0 = ty * 4, px0 = tx * 4;
    const int iy0 = py0 * 2, ix0 = px0 * 2;

    __shared__ uint32 tin[12 * 12 * 32];

    const int tid = threadIdx.x;

    const float* hb = h1 + (size_t)b * 8 * 29768;
    for (int s = tid; s < 288; s += 256) {
        const int pos = s >> 1, wqs = s & 1;
        const int r = pos / 12, c = pos % 12;
        const float* base = hb + ((size_t)(iy0 + r) * 61 + ix0 + c) * 8 + wqs * 4;
        const float4 f0 = *reinterpret_cast<const float4*>(base);
        const float4 f1 = *reinterpret_cast<const float4*>(base + 29768);
        const float4 f2 = *reinterpret_cast<const float4*>(base + 2 * 29768);
        const float4 f3 = *reinterpret_cast<const float4*>(base + 3 * 29768);
        const float4 f4 = *reinterpret_cast<const float4*>(base + 4 * 29768);
        const float4 f5 = *reinterpret_cast<const float4*>(base + 5 * 29768);
        const float4 f6 = *reinterpret_cast<const float4*>(base + 6 * 29768);
        const float4 f7 = *reinterpret_cast<const float4*>(base + 7 * 29768);
        const int sw = pos & 7;
        const int bi = pos * 32;
        *reinterpret_cast<uint4*>(&tin[bi + (((wqs * 4 + 0) ^ sw) << 2)]) =
            make_uint4(pkrtz(f0.x, f1.x), pkrtz(f2.x, f3.x), pkrtz(f4.x, f5.x), pkrtz(f6.x, f7.x));
        *reinterpret_cast<uint4*>(&tin[bi + (((wqs * 4 + 1) ^ sw) << 2)]) =
            make_uint4(pkrtz(f0.y, f1.y), pkrtz(f2.y, f3.y), pkrtz(f4.y, f5.y), pkrtz(f6.y, f7.y));
        *reinterpret_cast<uint4*>(&tin[bi + (((wqs * 4 + 2) ^ sw) << 2)]) =
            make_uint4(pkrtz(f0.z, f1.z), pkrtz(f2.z, f3.z), pkrtz(f4.z, f5.z), pkrtz(f6.z, f7.z));
        *reinterpret_cast<uint4*>(&tin[bi + (((wqs * 4 + 3) ^ sw) << 2)]) =
            make_uint4(pkrtz(f0.w, f1.w), pkrtz(f2.w, f3.w), pkrtz(f4.w, f5.w), pkrtz(f6.w, f7.w));
    }

    const int lane = tid & 63;
    const int wv   = tid >> 6;         // pooled row
    const int kc   = lane >> 4;
    const int arow = lane & 15;
    const int q    = arow >> 2, cp = arow & 3;
    const int cpy  = cp >> 1,  cpx = cp & 1;

    f16x8 Bf[7];
#pragma unroll
    for (int ks = 0; ks < 7; ++ks) {
        const uint4 t = *reinterpret_cast<const uint4*>(wt2m + (ks * 64 + lane) * 4);
        Bf[ks] = __builtin_bit_cast(f16x8, t);
    }

    int offp[7], sw2[7];
#pragma unroll
    for (int ks = 0; ks < 7; ++ks) {
        int tap = 4 * ks + kc;
        if (tap > 24) tap = 24;        // B is zero there
        const int kd = tap / 5, kh = tap % 5;
        const int pos = (2 * wv + cpy + kd) * 12 + (2 * q + cpx + kh);
        offp[ks] = pos * 32;
        sw2[ks]  = pos & 7;
    }

    __syncthreads();

    f32x4 acc[8];
#pragma unroll
    for (int w = 0; w < 8; ++w) acc[w] = (f32x4)(0.f);

#pragma unroll
    for (int w = 0; w < 8; ++w) {
#pragma unroll
        for (int ks = 0; ks < 7; ++ks) {
            const uint4 a4 = *reinterpret_cast<const uint4*>(
                &tin[offp[ks] + (((w ^ sw2[ks])) << 2)]);
            acc[w] = __builtin_amdgcn_mfma_f32_16x16x32_f16(
                __builtin_bit_cast(f16x8, a4), Bf[ks], acc[w], 0, 0, 0);
        }
    }

    const int oc = lane & 15, qo = lane >> 4;
    const int pi = py0 + wv, pjg = px0 + qo;   // < 28 always
    if (oc < 10) {
        const float bb = b2[oc];
        float vals[8];
#pragma unroll
        for (int w = 0; w < 8; ++w) {
            const float m = fmaxf(fmaxf(acc[w][0], acc[w][1]), fmaxf(acc[w][2], acc[w][3]));
            vals[w] = fmaxf(m + bb, 0.f);
        }
        float* base = h2 + ((((size_t)b * 10 + oc) * 28 + pi) * 28 + pjg) * 8;
        *reinterpret_cast<float4*>(base)     = make_float4(vals[0], vals[1], vals[2], vals[3]);
        *reinterpret_cast<float4*>(base + 4) = make_float4(vals[4], vals[5], vals[6], vals[7]);
    }
}

// ---------------- K3: fc1 (62720 -> 32), split-K, partials to ws ----------------
__global__ __launch_bounds__(256) void k_fc1(const float* __restrict__ feat,
                                             const float* __restrict__ w,
                                             float* __restrict__ partials) {
    const int j = blockIdx.x >> 4;
    const int kc = blockIdx.x & 15;
    const int k0 = kc * 3920;
    const float4* w4 = reinterpret_cast<const float4*>(w + (size_t)j * 62720 + k0);
    float acc[8];
#pragma unroll
    for (int b = 0; b < 8; ++b) acc[b] = 0.f;
    for (int i = threadIdx.x; i < 980; i += 256) {
        const float4 wv = w4[i];
#pragma unroll
        for (int b = 0; b < 8; ++b) {
            const float4 fv = *reinterpret_cast<const float4*>(feat + (size_t)b * 62720 + k0 + i * 4);
            acc[b] = fmaf(wv.x, fv.x, fmaf(wv.y, fv.y, fmaf(wv.z, fv.z, fmaf(wv.w, fv.w, acc[b]))));
        }
    }
#pragma unroll
    for (int b = 0; b < 8; ++b)
#pragma unroll
        for (int off = 32; off > 0; off >>= 1) acc[b] += __shfl_down(acc[b], off);
    __shared__ float red[4][8];
    const int wave = threadIdx.x >> 6;
    if ((threadIdx.x & 63) == 0)
#pragma unroll
        for (int b = 0; b < 8; ++b) red[wave][b] = acc[b];
    __syncthreads();
    if (threadIdx.x < 8) {
        partials[(j * 16 + kc) * 8 + threadIdx.x] =
            red[0][threadIdx.x] + red[1][threadIdx.x] + red[2][threadIdx.x] + red[3][threadIdx.x];
    }
}

// ---------------- K4: fc1-reduce + fc2 + rigid (in-block) + flow + sample + moved ------
__global__ __launch_bounds__(256) void k_flow_all(const float* __restrict__ x,
                                                  const float* __restrict__ partials,
                                                  const float* __restrict__ f1b,
                                                  const float* __restrict__ f2w,
                                                  const float* __restrict__ f2b,
                                                  const float* __restrict__ pos,
                                                  const float* __restrict__ centers,
                                                  float* __restrict__ outXt,
                                                  float* __restrict__ outGrid,
                                                  float* __restrict__ movedOut,
                                                  float* __restrict__ regOut) {
    const int b = blockIdx.y;
    const int tid = threadIdx.x;
    const int l = blockIdx.x * 256 + tid;

    __shared__ float sfo[32];
    __shared__ float srt[64];
    __shared__ float sg[768];
    __shared__ float red[128];

    if (tid < 32) {
        float s = 0.f;
#pragma unroll
        for (int kc = 0; kc < 16; ++kc) s += partials[(tid * 16 + kc) * 8 + b];
        sfo[tid] = fmaxf(s + f1b[tid], 0.f);
    }
    __syncthreads();
    if (tid < 8) {
        const int t = tid;
        float th[6];
#pragma unroll
        for (int i = 0; i < 6; ++i) {
            const int o = t * 6 + i;
            float s = f2b[o];
            const float* wr = f2w + o * 32;
#pragma unroll
            for (int k = 0; k < 32; ++k) s = fmaf(sfo[k], wr[k], s);
            th[i] = tanhf(s);
        }
        float s0, c0, s1, c1, s2, c2;
        sincosf(PI_F * th[0], &s0, &c0);
        sincosf(PI_F * th[1], &s1, &c1);
        sincosf(PI_F * th[2], &s2, &c2);
        const float R00 = c0 * c1, R10 = s0 * c1, R20 = -s1;
        const float R01 = -s0 * c2 + c0 * s1 * s2;
        const float R11 =  c0 * c2 + s0 * s1 * s2;
        const float R21 =  c1 * s2;
        const float T0 = th[3] * 128.f + 64.f - (64.f * R00 + 64.f * R10 + 4.f * R20);
        const float T1 = th[4] * 128.f + 64.f - (64.f * R01 + 64.f * R11 + 4.f * R21);
        float* o = srt + t * 8;
        o[0] = R00; o[1] = R10; o[2] = R20; o[3] = T0;
        o[4] = R01; o[5] = R11; o[6] = R21; o[7] = T1;
    }
    __syncthreads();

    const float gi = (float)(l >> 10);
    const float gj = (float)((l >> 3) & 127);
    const float gk = (float)(l & 7);

    const float tsx[8] = {32.f, 32.f, 96.f, 96.f, 32.f, 96.f, 64.f, 64.f};
    const float tsy[8] = {32.f, 96.f, 32.f, 96.f, 64.f, 64.f, 32.f, 96.f};

    float u0 = 0.f, u1 = 0.f, es = 0.f;
#pragma unroll
    for (int t = 0; t < 8; ++t) {
        float dx = gi - tsx[t], dy = gj - tsy[t], dz = gk - 4.f;
        float d = sqrtf(dx * dx + dy * dy + dz * dz);
        float e = expf(-d / 10.f);
        const float4 ra = *reinterpret_cast<const float4*>(&srt[t * 8]);
        const float4 rb = *reinterpret_cast<const float4*>(&srt[t * 8 + 4]);
        float f0 = fmaf(gi, ra.x, fmaf(gj, ra.y, fmaf(gk, ra.z, ra.w)));
        float f1 = fmaf(gi, rb.x, fmaf(gj, rb.y, fmaf(gk, rb.z, rb.w)));
        u0 = fmaf(e, f0, u0);
        u1 = fmaf(e, f1, u1);
        es += e;
    }
    const float inv = 1.f / es;
    const float fs0 = u0 * inv, fs1 = u1 * inv;
    const float nf0 = fs0 * (1.f / 64.f) - 1.f;
    const float nf1 = fs1 * (1.f / 64.f) - 1.f;

    sg[tid * 3 + 0] = 0.f;
    sg[tid * 3 + 1] = nf1;
    sg[tid * 3 + 2] = nf0;
    __syncthreads();
    if (tid < 192) {
        *reinterpret_cast<float4*>(outGrid + (size_t)b * 393216 + (size_t)blockIdx.x * 768 +
                                   tid * 4) = *reinterpret_cast<float4*>(&sg[tid * 4]);
    }

    const float iz = fs0 - 0.5f, iy = fs1 - 0.5f;
    const float z0f = floorf(iz), y0f = floorf(iy);
    const float fz = iz - z0f, fy = iy - y0f;
    const int z0 = (int)z0f, y0 = (int)y0f;
    float s0 = 0.f, s1 = 0.f, s2 = 0.f, s3 = 0.f;
    const float* xb = x + (size_t)b * 4 * 131072;
#pragma unroll
    for (int dz = 0; dz < 2; ++dz) {
        const int zc = z0 + dz;
        if (zc < 0 || zc > 127) continue;
        const float wz = dz ? fz : 1.f - fz;
#pragma unroll
        for (int dy = 0; dy < 2; ++dy) {
            const int yc = y0 + dy;
            if (yc < 0 || yc > 127) continue;
            const float wv = wz * (dy ? fy : 1.f - fy) * 0.5f;
            const float* p = xb + ((size_t)zc * 128 + yc) * 8 + 3;
            s0 = fmaf(wv, p[0] + p[1], s0);
            s1 = fmaf(wv, p[131072] + p[131073], s1);
            s2 = fmaf(wv, p[262144] + p[262145], s2);
            s3 = fmaf(wv, p[393216] + p[393217], s3);
        }
    }
    float* o = outXt + (size_t)b * 4 * 131072 + l;
    o[0] = s0; o[131072] = s1; o[262144] = s2; o[393216] = s3;

    if (blockIdx.x == 0) {
        float nrm = 0.f;
        if (tid < 128) {
            const int p = tid;
            if (p < 100) {
                const float* pp = pos + ((size_t)b * 100 + p) * 3;
                const float p0 = pp[0], p1 = pp[1], p2 = pp[2];
                int i0 = (int)rintf(p0); i0 = i0 < 0 ? 0 : (i0 > 127 ? 127 : i0);
                int i1 = (int)rintf(p1); i1 = i1 < 0 ? 0 : (i1 > 127 ? 127 : i1);
                int i2 = (int)rintf(p2); i2 = i2 < 0 ? 0 : (i2 > 7 ? 7 : i2);
                const float qi = (float)i0, qj = (float)i1, qk = (float)i2;
                float v0 = 0.f, v1 = 0.f, esm = 0.f;
#pragma unroll
                for (int t = 0; t < 8; ++t) {
                    float dx = qi - tsx[t], dy = qj - tsy[t], dz = qk - 4.f;
                    float d = sqrtf(dx * dx + dy * dy + dz * dz);
                    float e = expf(-d / 10.f);
                    const float* r = srt + t * 8;
                    float f0 = fmaf(qi, r[0], fmaf(qj, r[1], fmaf(qk, r[2], r[3])));
                    float f1 = fmaf(qi, r[4], fmaf(qj, r[5], fmaf(qk, r[6], r[7])));
                    v0 = fmaf(e, f0, v0);
                    v1 = fmaf(e, f1, v1);
                    esm += e;
                }
                const float invm = 1.f / esm;
                const float m0 = 2.f * p0 - (0.5f + 0.5f * ((v0 * invm) * (1.f / 64.f) - 1.f)) * 127.f;
                const float m1 = 2.f * p1 - (0.5f + 0.5f * ((v1 * invm) * (1.f / 64.f) - 1.f)) * 127.f;
                const float m2 = 2.f * p2 - 3.5f;
                float* mo = movedOut + ((size_t)b * 100 + p) * 3;
                mo[0] = m0; mo[1] = m1; mo[2] = m2;
                const float* ce = centers + p * 3;
                const float d0 = m0 - ce[0], d1 = m1 - ce[1], d2 = m2 - ce[2];
                nrm = sqrtf(d0 * d0 + d1 * d1 + d2 * d2);
            }
            red[tid] = nrm;
        }
        __syncthreads();
        for (int s = 64; s > 0; s >>= 1) {
            if (tid < s) red[tid] += red[tid + s];
            __syncthreads();
        }
        if (tid == 0) regOut[b] = red[0] * 0.01f;
    }
}

// ---------------- launch ----------------
extern "C" void kernel_launch(void* const* d_in, const int* in_sizes, int n_in,
                              void* d_out, int out_size, void* d_ws, size_t ws_size,
                              hipStream_t stream) {
    const float* x       = (const float*)d_in[0];
    const float* pos     = (const float*)d_in[1];
    const float* centers = (const float*)d_in[2];
    const float* c1w     = (const float*)d_in[3];
    const float* c1b     = (const float*)d_in[4];
    const float* c2w     = (const float*)d_in[5];
    const float* c2b     = (const float*)d_in[6];
    const float* f1w     = (const float*)d_in[7];
    const float* f1b     = (const float*)d_in[8];
    const float* f2w     = (const float*)d_in[9];
    const float* f2b     = (const float*)d_in[10];

    float* out = (float*)d_out;
    float* ws  = (float*)d_ws;

    // workspace layout (floats)
    float* h1       = ws;                      // 8*8*61*61*8   = 1,905,152
    float* h2       = h1 + 1905152;            // 8*10*28*28*8  =   501,760
    float* partials = h2 + 501760;             // 32*16*8       =     4,096

    // output layout (floats): X_t | grid | reg | moved
    float* outXt    = out;                         // 4,194,304
    float* outGrid  = out + 4194304;               // 3,145,728
    float* outReg   = out + 4194304 + 3145728;     // 8
    float* outMoved = outReg + 8;                  // 2,400

    // weight stash in tail of outGrid — fully overwritten by k_flow_all afterwards
    uint32* wt1m = (uint32*)(out + 4194304 + 3145728 - 4096);   // 1792 dwords
    uint32* wt2m = wt1m + 1792;                                  // 1792 dwords

    k_prep<<<1, 256, 0, stream>>>(c1w, c2w, wt1m, wt2m);
    k_conv1<<<dim3(256, 8), 256, 0, stream>>>(x, wt1m, c1b, h1);
    k_conv2<<<dim3(49, 8), 256, 0, stream>>>(h1, wt2m, c2b, h2);
    k_fc1<<<512, 256, 0, stream>>>(h2, f1w, partials);
    k_flow_all<<<dim3(512, 8), 256, 0, stream>>>(x, partials, f1b, f2w, f2b, pos, centers,
                                                 outXt, outGrid, outMoved, outReg);
}